// Round 13
// baseline (207.707 us; speedup 1.0000x reference)
//
#include <hip/hip_runtime.h>

// CrossTransformerLayer on MI355X — round 13.
// Change vs round 12 (best, 200.5us): k_attn_up block = (j, h, i-chunk of 2):
// K/V staged ONCE per block, serial loop over 2 query sequences i (per-wave
// independent; both masks preloaded -> single barrier). 2048 -> 1024 attn
// blocks, staging halved. #pragma unroll 1 on the i-loop (r8 lesson).

using u16 = unsigned short;
using u32 = unsigned int;
typedef __attribute__((ext_vector_type(8))) short short8;
typedef __attribute__((ext_vector_type(4))) float f32x4;

__device__ __forceinline__ u32 cvtpk(float lo, float hi) {
  u32 r;
  asm("v_cvt_pk_bf16_f32 %0, %1, %2" : "=v"(r) : "v"(lo), "v"(hi));
  return r;
}
__device__ __forceinline__ u16 f2bf(float f) { return (u16)cvtpk(f, f); }
__device__ __forceinline__ float bf2f(u16 h) {
  return __uint_as_float(((u32)h) << 16);
}
__device__ __forceinline__ float exp2a(float x) {
  float r;
  asm("v_exp_f32 %0, %1" : "=v"(r) : "v"(x));
  return r;
}
__device__ __forceinline__ f32x4 mfma16(short8 a, short8 b, f32x4 c) {
  return __builtin_amdgcn_mfma_f32_16x16x32_bf16(a, b, c, 0, 0, 0);
}
__device__ __forceinline__ void gload16(const void* g, u16* l) {
  __builtin_amdgcn_global_load_lds(
      (const __attribute__((address_space(1))) void*)g,
      (__attribute__((address_space(3))) void*)l, 16, 0, 0);
}

// ---------------- staging (BK=64 cols, row stride 64 elems, 16B-slot swizzle) ----
template<int ROWS, int NT>
__device__ __forceinline__ void stage_g16(u16* lds, const u16* __restrict__ src,
                                          int ld, int tid) {
  constexpr int UNITS = ROWS * 8;
  constexpr int WV = NT / 64;
  int lane = tid & 63, w = tid >> 6;
  #pragma unroll
  for (int u = 0; u < UNITS / NT; ++u) {
    int base = (u * WV + w) * 64;
    int unit = base + lane;
    int row = unit >> 3, co = unit & 7;
    gload16(src + (long)row * ld + ((co ^ (row & 7)) << 3), lds + base * 8);
  }
}
template<int ROWS, int NT>
__device__ __forceinline__ void stage_f32(u16* lds, const float* __restrict__ src,
                                          int ld, int tid) {
  constexpr int UNITS = ROWS * 8;
  #pragma unroll
  for (int u = 0; u < UNITS / NT; ++u) {
    int unit = tid + u * NT;
    int row = unit >> 3, co = unit & 7;
    const float* g = src + (long)row * ld + (co << 3);
    float4 a = *(const float4*)g;
    float4 b = *(const float4*)(g + 4);
    u32 p[4] = {cvtpk(a.x, a.y), cvtpk(a.z, a.w),
                cvtpk(b.x, b.y), cvtpk(b.z, b.w)};
    *(uint4*)&lds[(row << 6) + ((co ^ (row & 7)) << 3)] = *(const uint4*)p;
  }
}

// ---------------- generic GEMM core: D = A @ B^T (1-phase, small shapes) ------
template<typename AT, typename BT, int BM, int BN, int WM, int WN>
__device__ __forceinline__ void gemm_core(const AT* __restrict__ A, int lda,
                                          const BT* __restrict__ Bt, int ldb, int K,
                                          u16* As, u16* Bs,
                                          f32x4 (&acc)[BM / (WM * 16)][BN / (WN * 16)]) {
  constexpr int NT = WM * WN * 64;
  constexpr int MI = BM / (WM * 16), NJ = BN / (WN * 16);
  int tid = threadIdx.x, lane = tid & 63, wid = tid >> 6;
  int wr = wid % WM, wc = wid / WM;
  int g = lane >> 4, c = lane & 15;
  #pragma unroll
  for (int mi = 0; mi < MI; ++mi)
    #pragma unroll
    for (int nj = 0; nj < NJ; ++nj)
      acc[mi][nj] = f32x4{0.f, 0.f, 0.f, 0.f};
  for (int kb = 0; kb < K; kb += 64) {
    __syncthreads();
    if constexpr (sizeof(AT) == 4) stage_f32<BM, NT>(As, A + kb, lda, tid);
    else                           stage_g16<BM, NT>(As, A + kb, lda, tid);
    if constexpr (sizeof(BT) == 4) stage_f32<BN, NT>(Bs, Bt + kb, ldb, tid);
    else                           stage_g16<BN, NT>(Bs, Bt + kb, ldb, tid);
    __syncthreads();
    #pragma unroll
    for (int kk = 0; kk < 2; ++kk) {
      int sl = ((kk * 4 + g) ^ (c & 7)) << 3;
      short8 af[MI], bfr[NJ];
      #pragma unroll
      for (int mi = 0; mi < MI; ++mi)
        af[mi] = *(const short8*)&As[((wr * (BM / WM) + mi * 16 + c) << 6) + sl];
      #pragma unroll
      for (int nj = 0; nj < NJ; ++nj)
        bfr[nj] = *(const short8*)&Bs[((wc * (BN / WN) + nj * 16 + c) << 6) + sl];
      #pragma unroll
      for (int mi = 0; mi < MI; ++mi)
        #pragma unroll
        for (int nj = 0; nj < NJ; ++nj)
          acc[mi][nj] = mfma16(af[mi], bfr[nj], acc[mi][nj]);
    }
  }
}

// ---------------- fused prep: S cast (768 blocks) + weight transpose ----------
struct TJob { const float* src; u16* dst; int R, C, tile0; };
struct TJobs { TJob j[9]; };

__global__ __launch_bounds__(256) void k_prep(const float* __restrict__ S,
                                              u16* __restrict__ Sb, TJobs jobs) {
  __shared__ float tile[32][33];
  int bid = blockIdx.x;
  if (bid < 768) {  // cast S fp32 -> bf16
    int idx = (bid * 256 + threadIdx.x) * 8;
    float4 a = *(const float4*)(S + idx);
    float4 b = *(const float4*)(S + idx + 4);
    u32 p[4] = {cvtpk(a.x, a.y), cvtpk(a.z, a.w),
                cvtpk(b.x, b.y), cvtpk(b.z, b.w)};
    *(uint4*)(Sb + idx) = *(const uint4*)p;
    return;
  }
  int t = bid - 768;
  int ji = 0;
  #pragma unroll
  for (int k = 1; k < 9; ++k)
    if (t >= jobs.j[k].tile0) ji = k;
  TJob jb = jobs.j[ji];
  int lt = t - jb.tile0;
  int tpr = jb.C >> 5;
  int tr = lt / tpr, tc = lt % tpr;
  int tid = threadIdx.x;
  #pragma unroll
  for (int u = 0; u < 4; ++u) {
    int e = tid + u * 256;
    int r = e >> 5, cc = e & 31;
    tile[r][cc] = jb.src[(long)(tr * 32 + r) * jb.C + tc * 32 + cc];
  }
  __syncthreads();
  #pragma unroll
  for (int u = 0; u < 4; ++u) {
    int e = tid + u * 256;
    int r = e >> 5, cc = e & 31;
    jb.dst[(long)(tc * 32 + r) * jb.R + tr * 32 + cc] = f2bf(tile[cc][r]);
  }
}

// ---------------- G1: unified QKV+iaQ projection (bf16 GEMM, N=2048) ----------
__global__ __launch_bounds__(256) void k_qkv(const u16* __restrict__ Sb,
    const u16* __restrict__ btAll,
    const float* __restrict__ b0, const float* __restrict__ b1,
    const float* __restrict__ b2, const float* __restrict__ b3,
    u16* __restrict__ Qc, u16* __restrict__ Kc, u16* __restrict__ Vt,
    u16* __restrict__ Qi) {
  __shared__ u16 SH[16384];
  int f = blockIdx.x;                       // 384 blocks
  int swz = (f & 7) * 48 + (f >> 3);
  int mb = swz >> 4, nb = swz & 15;
  f32x4 acc[4][4];
  gemm_core<u16, u16, 128, 128, 2, 2>(Sb + (long)mb * 128 * 512, 512,
                                      btAll + (long)nb * 128 * 512, 512, 512,
                                      SH, SH + 8192, acc);
  int z = nb >> 2;
  const float* bias = z == 0 ? b0 : z == 1 ? b1 : z == 2 ? b2 : b3;
  // z==0: Qc scaled by 1/8 * log2(e) so CA softmax can use exp2 directly.
  float scale = z == 0 ? 0.18033688011112042f : (z == 3 ? 0.125f : 1.0f);
  int lane = threadIdx.x & 63, wid = threadIdx.x >> 6;
  int wr = wid & 1, wc = wid >> 1, g = lane >> 4, cl = lane & 15;
  #pragma unroll
  for (int mi = 0; mi < 4; ++mi)
    #pragma unroll
    for (int nj = 0; nj < 4; ++nj)
      #pragma unroll
      for (int r = 0; r < 4; ++r) {
        int row = mb * 128 + wr * 64 + mi * 16 + g * 4 + r;
        int cz = (nb & 3) * 128 + wc * 64 + nj * 16 + cl;
        float v = (acc[mi][nj][r] + bias[cz]) * scale;
        int seq = row / 192, t = row % 192, h = cz >> 6, hd = cz & 63;
        if (z == 0)      Qc[((long)(seq * 8 + h) * 192 + t) * 64 + hd] = f2bf(v);
        else if (z == 1) Kc[((long)(seq * 8 + h) * 192 + t) * 64 + hd] = f2bf(v);
        else if (z == 2) Vt[((long)(seq * 8 + h) * 64 + hd) * 192 + t] = f2bf(v);
        else             Qi[(long)row * 512 + cz] = f2bf(v);
      }
}

// ---------------- G2: CA attention (K/V staged once, 2 i per block) + uproj ---
// attn block: bid -> j = bid>>6, h = (bid>>3)&7, ic = bid&7; i in {2ic, 2ic+1}.
__global__ __launch_bounds__(256) void k_attn_up(const u16* __restrict__ Qc,
    const u16* __restrict__ Kc, const u16* __restrict__ VtG,
    const int* __restrict__ mask, u16* __restrict__ AC,
    const u16* __restrict__ Qi, const float* __restrict__ wk,
    u16* __restrict__ U, int attnBlocks) {
  __shared__ __align__(16) u16 SH[25344];   // 50688 B -> 3 blocks/CU
  int bid = blockIdx.x;
  int tid = threadIdx.x, lane = tid & 63, w = tid >> 6;
  int g = lane >> 4, c = lane & 15;
  if (bid < attnBlocks) {
    u16* Ks = SH;                            // 24576 B
    u16* Vs = SH + 12288;                    // 24576 B
    float* mbf = (float*)(SH + 24576);       // 2 x 192 floats
    int j = bid >> 6, h = (bid >> 3) & 7, ic = bid & 7;
    int qb = w * 48;

    const u16* Kbase = Kc + (long)(j * 8 + h) * 192 * 64;
    #pragma unroll
    for (int u = 0; u < 6; ++u) {
      int base = (u * 4 + w) * 64;
      int unit = base + lane;
      int row = unit >> 3, co = unit & 7;
      gload16(Kbase + (long)row * 64 + ((co ^ (row & 7)) << 3), Ks + base * 8);
    }
    const u16* Vbase = VtG + (long)(j * 8 + h) * 64 * 192;
    #pragma unroll
    for (int u = 0; u < 6; ++u) {
      int base = (u * 4 + w) * 64;
      int unit = base + lane;
      int row = unit / 24, co = unit - row * 24;
      gload16(Vbase + (long)row * 192 + ((co ^ (row & 7)) << 3), Vs + base * 8);
    }
    if (tid < 192) {
      mbf[tid]       = mask[(long)((ic * 2 + 0) * 16 + j) * 192 + tid] ? 0.f : -1e9f;
      mbf[192 + tid] = mask[(long)((ic * 2 + 1) * 16 + j) * 192 + tid] ? 0.f : -1e9f;
    }
    __syncthreads();

    int srcLo = c | ((g & 1) << 5);
    int srcHi = srcLo + 16;
    int hi = g & 2;

    #pragma unroll 1
    for (int ii = 0; ii < 2; ++ii) {
      int i = ic * 2 + ii;
      int b = i * 16 + j;
      short8 bq[3][2];
      const u16* Qbase = Qc + (long)(i * 8 + h) * 192 * 64;
      #pragma unroll
      for (int nj = 0; nj < 3; ++nj)
        #pragma unroll
        for (int ks = 0; ks < 2; ++ks)
          bq[nj][ks] = *(const short8*)(Qbase + (long)(qb + nj * 16 + c) * 64 + ks * 32 + g * 8);

      f32x4 oa[4][3];
      #pragma unroll
      for (int mi = 0; mi < 4; ++mi)
        #pragma unroll
        for (int nj = 0; nj < 3; ++nj)
          oa[mi][nj] = f32x4{0.f, 0.f, 0.f, 0.f};
      float sm[3] = {0.f, 0.f, 0.f};

      for (int s = 0; s < 6; ++s) {
        short8 ak[2][2];
        #pragma unroll
        for (int kh = 0; kh < 2; ++kh) {
          int row = (2 * s + kh) * 16 + c;
          #pragma unroll
          for (int ks = 0; ks < 2; ++ks)
            ak[kh][ks] = *(const short8*)&Ks[(row << 6) + (((ks * 4 + g) ^ (c & 7)) << 3)];
        }
        f32x4 sa[2][3];
        __builtin_amdgcn_s_setprio(1);
        #pragma unroll
        for (int kh = 0; kh < 2; ++kh)
          #pragma unroll
          for (int nj = 0; nj < 3; ++nj) {
            sa[kh][nj] = mfma16(ak[kh][0], bq[nj][0], f32x4{0.f, 0.f, 0.f, 0.f});
            sa[kh][nj] = mfma16(ak[kh][1], bq[nj][1], sa[kh][nj]);
          }
        __builtin_amdgcn_s_setprio(0);
        u32 pk[2][3][2];
        #pragma unroll
        for (int kh = 0; kh < 2; ++kh) {
          f32x4 m4 = *(const f32x4*)&mbf[ii * 192 + (2 * s + kh) * 16 + g * 4];
          #pragma unroll
          for (int nj = 0; nj < 3; ++nj) {
            float p0 = exp2a(sa[kh][nj][0] + m4[0]);
            float p1 = exp2a(sa[kh][nj][1] + m4[1]);
            float p2 = exp2a(sa[kh][nj][2] + m4[2]);
            float p3 = exp2a(sa[kh][nj][3] + m4[3]);
            sm[nj] += (p0 + p1) + (p2 + p3);
            pk[kh][nj][0] = cvtpk(p0, p1);
            pk[kh][nj][1] = cvtpk(p2, p3);
          }
        }
        short8 bfg[3];
        #pragma unroll
        for (int nj = 0; nj < 3; ++nj) {
          u32 w0a = (u32)__shfl((int)pk[0][nj][0], srcLo);
          u32 w0b = (u32)__shfl((int)pk[1][nj][0], srcLo);
          u32 w1a = (u32)__shfl((int)pk[0][nj][1], srcLo);
          u32 w1b = (u32)__shfl((int)pk[1][nj][1], srcLo);
          u32 w2a = (u32)__shfl((int)pk[0][nj][0], srcHi);
          u32 w2b = (u32)__shfl((int)pk[1][nj][0], srcHi);
          u32 w3a = (u32)__shfl((int)pk[0][nj][1], srcHi);
          u32 w3b = (u32)__shfl((int)pk[1][nj][1], srcHi);
          union { u32 u[4]; short8 s8; } bf;
          bf.u[0] = hi ? w0b : w0a;
          bf.u[1] = hi ? w1b : w1a;
          bf.u[2] = hi ? w2b : w2a;
          bf.u[3] = hi ? w3b : w3a;
          bfg[nj] = bf.s8;
        }
        int sl = ((s * 4 + g) ^ (c & 7)) << 3;
        __builtin_amdgcn_s_setprio(1);
        #pragma unroll
        for (int mi = 0; mi < 4; ++mi) {
          short8 av = *(const short8*)&Vs[(mi * 16 + c) * 192 + sl];
          #pragma unroll
          for (int nj = 0; nj < 3; ++nj)
            oa[mi][nj] = mfma16(av, bfg[nj], oa[mi][nj]);
        }
        __builtin_amdgcn_s_setprio(0);
      }
      #pragma unroll
      for (int nj = 0; nj < 3; ++nj) {
        sm[nj] += __shfl_xor(sm[nj], 16);
        sm[nj] += __shfl_xor(sm[nj], 32);
      }
      #pragma unroll
      for (int nj = 0; nj < 3; ++nj) {
        float rs = 1.0f / sm[nj];
        int q = qb + nj * 16 + c;
        u16* dst = AC + ((long)(b * 192 + q)) * 512 + h * 64 + g * 4;
        #pragma unroll
        for (int mi = 0; mi < 4; ++mi) {
          u32 p2[2] = {cvtpk(oa[mi][nj][0] * rs, oa[mi][nj][1] * rs),
                       cvtpk(oa[mi][nj][2] * rs, oa[mi][nj][3] * rs)};
          *(uint2*)(dst + mi * 16) = *(const uint2*)p2;
        }
      }
    }
  } else {
    u16* As = SH;
    u16* Bs = SH + 8192;
    int t = bid - attnBlocks;
    int mb = t % 24, r2 = t / 24;
    int nb = r2 & 3, h = r2 >> 2;
    f32x4 acc[4][4];
    gemm_core<u16, float, 128, 128, 2, 2>(Qi + (long)mb * 128 * 512 + h * 64, 512,
                                          wk + (long)nb * 128 * 512 + h * 64, 512, 64,
                                          As, Bs, acc);
    int wr = w & 1, wc = w >> 1, cl = lane & 15;
    #pragma unroll
    for (int mi = 0; mi < 4; ++mi)
      #pragma unroll
      for (int nj = 0; nj < 4; ++nj)
        #pragma unroll
        for (int r = 0; r < 4; ++r) {
          int row = mb * 128 + wr * 64 + mi * 16 + g * 4 + r;
          int col = nb * 128 + wc * 64 + nj * 16 + cl;
          U[((long)row * 8 + h) * 512 + col] = f2bf(acc[mi][nj][r]);
        }
  }
}

// ---------------- G3: CA out-proj — 256^2 8-phase pipelined GEMM ----------
__global__ __launch_bounds__(512, 1) void k_oproj8(const u16* __restrict__ AC,
    const u16* __restrict__ woT, const float* __restrict__ bo,
    u16* __restrict__ S2) {
  extern __shared__ u16 LDS[];
  int f = blockIdx.x;                       // 384 blocks
  int swz = (f & 7) * 48 + (f >> 3);
  int mb = swz >> 1, nb = swz & 1;
  int tid = threadIdx.x, lane = tid & 63, wid = tid >> 6;
  int wr = wid >> 2, wc = wid & 3;
  int g = lane >> 4, c = lane & 15;
  const u16* Abase = AC + (long)mb * 256 * 512;
  const u16* Bbase = woT + (long)nb * 256 * 512;

  auto STAGE = [&](int opOff, int buf, int half, int kt, const u16* base) {
    u16* ldst = LDS + opOff + buf * 16384 + half * 8192;
    const u16* gsrc = base + (long)half * 128 * 512 + kt * 64;
    #pragma unroll
    for (int u = 0; u < 2; ++u) {
      int unit = tid + u * 512;
      int row = unit >> 3, co = unit & 7;
      gload16(gsrc + (long)row * 512 + ((co ^ (row & 7)) << 3), ldst + unit * 8);
    }
  };

  f32x4 acc[8][4];
  #pragma unroll
  for (int mi = 0; mi < 8; ++mi)
    #pragma unroll
    for (int nj = 0; nj < 4; ++nj)
      acc[mi][nj] = f32x4{0.f, 0.f, 0.f, 0.f};

  STAGE(0, 0, 0, 0, Abase);     STAGE(0, 0, 1, 0, Abase);
  STAGE(32768, 0, 0, 0, Bbase); STAGE(32768, 0, 1, 0, Bbase);
  STAGE(0, 1, 0, 1, Abase);     STAGE(0, 1, 1, 1, Abase);
  STAGE(32768, 1, 0, 1, Bbase); STAGE(32768, 1, 1, 1, Bbase);
  asm volatile("s_waitcnt vmcnt(8)");
  __builtin_amdgcn_s_barrier();

  short8 aLo[8], aHi[8], bLo[4], bHi[4];
  for (int t = 0; t < 8; ++t) {
    int buf = t & 1;
    int abase = buf * 16384, bbase = 32768 + buf * 16384;
    #pragma unroll
    for (int m = 0; m < 4; ++m)
      #pragma unroll
      for (int kk = 0; kk < 2; ++kk)
        aLo[m * 2 + kk] = *(const short8*)&LDS[abase +
            (wr * 128 + m * 16 + c) * 64 + (((kk * 4 + g) ^ (c & 7)) << 3)];
    #pragma unroll
    for (int n = 0; n < 2; ++n)
      #pragma unroll
      for (int kk = 0; kk < 2; ++kk)
        bLo[n * 2 + kk] = *(const short8*)&LDS[bbase +
            (wc * 64 + n * 16 + c) * 64 + (((kk * 4 + g) ^ (c & 7)) << 3)];
    __builtin_amdgcn_s_barrier();
    asm volatile("s_waitcnt lgkmcnt(0)");
    __builtin_amdgcn_sched_barrier(0);
    __builtin_amdgcn_s_setprio(1);
    #pragma unroll
    for (int m = 0; m < 4; ++m)
      #pragma unroll
      for (int n = 0; n < 2; ++n)
        #pragma unroll
        for (int kk = 0; kk < 2; ++kk)
          acc[m][n] = mfma16(aLo[m * 2 + kk], bLo[n * 2 + kk], acc[m][n]);
    __builtin_amdgcn_s_setprio(0);
    __builtin_amdgcn_s_barrier();
    #pragma unroll
    for (int m = 0; m < 4; ++m)
      #pragma unroll
      for (int kk = 0; kk < 2; ++kk)
        aHi[m * 2 + kk] = *(const short8*)&LDS[abase +
            (wr * 128 + (4 + m) * 16 + c) * 64 + (((kk * 4 + g) ^ (c & 7)) << 3)];
    __builtin_amdgcn_s_barrier();
    asm volatile("s_waitcnt lgkmcnt(0)");
    __builtin_amdgcn_sched_barrier(0);
    __builtin_amdgcn_s_setprio(1);
    #pragma unroll
    for (int m = 0; m < 4; ++m)
      #pragma unroll
      for (int n = 0; n < 2; ++n)
        #pragma unroll
        for (int kk = 0; kk < 2; ++kk)
          acc[4 + m][n] = mfma16(aHi[m * 2 + kk], bLo[n * 2 + kk], acc[4 + m][n]);
    __builtin_amdgcn_s_setprio(0);
    __builtin_amdgcn_s_barrier();
    #pragma unroll
    for (int n = 0; n < 2; ++n)
      #pragma unroll
      for (int kk = 0; kk < 2; ++kk)
        bHi[n * 2 + kk] = *(const short8*)&LDS[bbase +
            (wc * 64 + (2 + n) * 16 + c) * 64 + (((kk * 4 + g) ^ (c & 7)) << 3)];
    if (t < 6) {
      STAGE(0, buf, 0, t + 2, Abase);
      STAGE(0, buf, 1, t + 2, Abase);
    }
    __builtin_amdgcn_s_barrier();
    asm volatile("s_waitcnt lgkmcnt(0)");
    __builtin_amdgcn_sched_barrier(0);
    __builtin_amdgcn_s_setprio(1);
    #pragma unroll
    for (int m = 0; m < 4; ++m)
      #pragma unroll
      for (int n = 0; n < 2; ++n)
        #pragma unroll
        for (int kk = 0; kk < 2; ++kk)
          acc[m][2 + n] = mfma16(aLo[m * 2 + kk], bHi[n * 2 + kk], acc[m][2 + n]);
    __builtin_amdgcn_s_setprio(0);
    __builtin_amdgcn_s_barrier();
    if (t < 6) {
      STAGE(32768, buf, 0, t + 2, Bbase);
      STAGE(32768, buf, 1, t + 2, Bbase);
    }
    __builtin_amdgcn_s_setprio(1);
    #pragma unroll
    for (int m = 0; m < 4; ++m)
      #pragma unroll
      for (int n = 0; n < 2; ++n)
        #pragma unroll
        for (int kk = 0; kk < 2; ++kk)
          acc[4 + m][2 + n] = mfma16(aHi[m * 2 + kk], bHi[n * 2 + kk], acc[4 + m][2 + n]);
    __builtin_amdgcn_s_setprio(0);
    if (t < 6)      asm volatile("s_waitcnt vmcnt(8)");
    else if (t == 6) asm volatile("s_waitcnt vmcnt(0)");
    if (t < 7) __builtin_amdgcn_s_barrier();
  }
  #pragma unroll
  for (int nj = 0; nj < 4; ++nj) {
    int col = nb * 256 + wc * 64 + nj * 16 + c;
    float bv = bo[col];
    #pragma unroll
    for (int mi = 0; mi < 8; ++mi)
      #pragma unroll
      for (int r = 0; r < 4; ++r) {
        int row = mb * 256 + wr * 128 + mi * 16 + g * 4 + r;
        S2[(long)row * 512 + col] = f2bf(acc[mi][nj][r] + bv);
      }
  }
}

// ---------------- G5: IA attention (MFMA logits + softmax + weighted-sum) -----
__global__ __launch_bounds__(256) void k_ia_attn(const u16* __restrict__ S2,
    const u16* __restrict__ U, const u16* __restrict__ Qi,
    const float* __restrict__ bk, u16* __restrict__ Y) {
  __shared__ u16 s2[16 * 520];
  __shared__ float Lp[4][16][17];
  __shared__ float aL[8][16];
  __shared__ float cL[8];
  int tok = blockIdx.x;
  int tid = threadIdx.x, lane = tid & 63, w = tid >> 6;
  {
    const u16* src = S2 + (long)tok * 512;
    #pragma unroll
    for (int u = 0; u < 4; ++u) {
      int e = tid + u * 256;
      int r = e >> 6, cc = (e & 63) << 3;
      *(uint4*)&s2[r * 520 + cc] = *(const uint4*)(src + (long)r * 3072 * 512 + cc);
    }
  }
  if (w == 0) {
    int h = lane >> 3, p = lane & 7;
    short8 qv = *(const short8*)(Qi + (long)tok * 512 + h * 64 + p * 8);
    const float* bkp = bk + h * 64 + p * 8;
    float s = 0.f;
    #pragma unroll
    for (int v = 0; v < 8; ++v) s += bf2f((u16)qv[v]) * bkp[v];
    s += __shfl_xor(s, 1); s += __shfl_xor(s, 2); s += __shfl_xor(s, 4);
    if (p == 0) cL[h] = s;
  }
  __syncthreads();
  {
    int g = lane >> 4, c = lane & 15;
    const u16* Ub = U + (long)tok * 4096 + (long)(c & 7) * 512;
    f32x4 accL = {0.f, 0.f, 0.f, 0.f};
    #pragma unroll
    for (int kk = 0; kk < 4; ++kk) {
      int d = w * 128 + kk * 32 + g * 8;
      short8 aS = *(const short8*)&s2[c * 520 + d];
      short8 bU = *(const short8*)(Ub + d);
      accL = mfma16(aS, bU, accL);
    }
    #pragma unroll
    for (int r = 0; r < 4; ++r) Lp[w][g * 4 + r][c] = accL[r];
  }
  __syncthreads();
  if (w == 0) {
    int h = lane & 7, i0 = lane >> 3;
    float L0 = Lp[0][i0][h] + Lp[1][i0][h] + Lp[2][i0][h] + Lp[3][i0][h] + cL[h];
    float L1 = Lp[0][i0 + 8][h] + Lp[1][i0 + 8][h] + Lp[2][i0 + 8][h] +
               Lp[3][i0 + 8][h] + cL[h];
    float e0 = __expf(L0), e1 = __expf(L1);
    float s = e0 + e1;
    s += __shfl_xor(s, 8); s += __shfl_xor(s, 16); s += __shfl_xor(s, 32);
    float rs = 1.0f / s;
    aL[h][i0] = e0 * rs;
    aL[h][i0 + 8] = e1 * rs;
  }
  __syncthreads();
  {
    int h = tid & 7, d0 = (tid >> 3) << 4;
    float y[16];
    #pragma unroll
    for (int v = 0; v < 16; ++v) y[v] = 0.f;
    #pragma unroll
    for (int i = 0; i < 16; ++i) {
      float a = aL[h][i];
      short8 v0 = *(const short8*)&s2[i * 520 + d0];
      short8 v1 = *(const short8*)&s2[i * 520 + d0 + 8];
      #pragma unroll
      for (int v = 0; v < 8; ++v) {
        y[v]     += a * bf2f((u16)v0[v]);
        y[8 + v] += a * bf2f((u16)v1[v]);
      }
    }
    u32 o[8];
    #pragma unroll
    for (int v = 0; v < 8; ++v) o[v] = cvtpk(y[2 * v], y[2 * v + 1]);
    u16* dst = Y + ((long)tok * 8 + h) * 512 + d0;
    *(uint4*)dst = *(const uint4*)&o[0];
    *(uint4*)(dst + 8) = *(const uint4*)&o[4];
  }
}

// ---------------- G6: attn_h = y_h @ Wv_h + bv ----------------
__global__ __launch_bounds__(256) void k_vapply(const u16* __restrict__ Y,
    const u16* __restrict__ wvT, const float* __restrict__ bv,
    u16* __restrict__ AO) {
  __shared__ u16 As[128 * 64];
  __shared__ u16 Bs[64 * 64];
  int mb = blockIdx.x, h = blockIdx.z;
  f32x4 acc[2][4];
  gemm_core<u16, u16, 128, 64, 4, 1>(Y + (long)mb * 128 * 4096 + h * 512, 4096,
                                     wvT + (long)h * 64 * 512, 512, 512,
                                     As, Bs, acc);
  int lane = threadIdx.x & 63, wid = threadIdx.x >> 6;
  int g = lane >> 4, cl = lane & 15;
  #pragma unroll
  for (int mi = 0; mi < 2; ++mi)
    #pragma unroll
    for (int nj = 0; nj < 4; ++nj)
      #pragma unroll
      for (int r = 0; r < 4; ++r) {
        int row = mb * 128 + wid * 32 + mi * 16 + g * 4 + r;
        int col = h * 64 + nj * 16 + cl;
        AO[(long)row * 512 + col] = f2bf(acc[mi][nj][r] + bv[col]);
      }
}

// ---------------- generic [3072,K]@[K,512] -> fp32, split-K=2 over grid.y -----
__global__ __launch_bounds__(256) void k_gemm_f32out(const u16* __restrict__ A, int K,
    const u16* __restrict__ BT, const float* __restrict__ bias,
    float* __restrict__ out) {
  __shared__ u16 As[128 * 64];
  __shared__ u16 Bs[64 * 64];
  int f = blockIdx.x;                       // 192 blocks per part
  int ks = blockIdx.y;
  int swz = (f & 7) * 24 + (f >> 3);
  int mb = swz >> 3, nb = swz & 7;
  int Kh = K >> 1;
  f32x4 acc[4][2];
  gemm_core<u16, u16, 128, 64, 2, 2>(A + (long)mb * 128 * K + (long)ks * Kh, K,
                                     BT + (long)nb * 64 * K + (long)ks * Kh, K,
                                     Kh, As, Bs, acc);
  out += (long)ks * 3072 * 512;
  int lane = threadIdx.x & 63, wid = threadIdx.x >> 6;
  int wr = wid & 1, wc = wid >> 1, g = lane >> 4, cl = lane & 15;
  #pragma unroll
  for (int mi = 0; mi < 4; ++mi)
    #pragma unroll
    for (int nj = 0; nj < 2; ++nj)
      #pragma unroll
      for (int r = 0; r < 4; ++r) {
        int row = mb * 128 + wr * 64 + mi * 16 + g * 4 + r;
        int col = nb * 64 + wc * 32 + nj * 16 + cl;
        float bv = ks == 0 ? bias[col] : 0.f;
        out[(long)row * 512 + col] = acc[mi][nj][r] + bv;
      }
}

// ---------------- G9: FFN1 with ReLU -> bf16 (XCD swizzle) ----------------
__global__ __launch_bounds__(256) void k_ffn1(const u16* __restrict__ A,
    const u16* __restrict__ BT, const float* __restrict__ bias,
    u16* __restrict__ out) {
  __shared__ u16 As[128 * 64];
  __shared__ u16 Bs[128 * 64];
  int f = blockIdx.x;                       // 384 blocks
  int swz = (f & 7) * 48 + (f >> 3);
  int mb = swz >> 4, nb = swz & 15;
  f32x4 acc[4][4];
  gemm_core<u16, u16, 128, 128, 2, 2>(A + (long)mb * 128 * 512, 512,
                                      BT + (long)nb * 128 * 512, 512, 512,
                                      As, Bs, acc);
  int lane = threadIdx.x & 63, wid = threadIdx.x >> 6;
  int wr = wid & 1, wc = wid >> 1, g = lane >> 4, cl = lane & 15;
  #pragma unroll
  for (int mi = 0; mi < 4; ++mi)
    #pragma unroll
    for (int nj = 0; nj < 4; ++nj)
      #pragma unroll
      for (int r = 0; r < 4; ++r) {
        int row = mb * 128 + wr * 64 + mi * 16 + g * 4 + r;
        int col = nb * 128 + wc * 64 + nj * 16 + cl;
        out[(long)row * 2048 + col] = f2bf(fmaxf(acc[mi][nj][r] + bias[col], 0.f));
      }
}

// ---------------- LayerNorm over D=512 of (X1+X2[+X3]) ----------------
__global__ __launch_bounds__(256) void k_ln(const float* __restrict__ X1,
    const float* __restrict__ X2, const float* __restrict__ X3,
    const float* __restrict__ gg, const float* __restrict__ bb,
    float* __restrict__ outF, u16* __restrict__ outB) {
  __shared__ float red[8];
  int row = blockIdx.x, tid = threadIdx.x;
  long base = (long)row * 512;
  float x0 = X1[base + tid] + X2[base + tid];
  float x1 = X1[base + tid + 256] + X2[base + tid + 256];
  if (X3) {
    x0 += X3[base + tid];
    x1 += X3[base + tid + 256];
  }
  float s = x0 + x1, ss = x0 * x0 + x1 * x1;
  #pragma unroll
  for (int m = 1; m <= 32; m <<= 1) {
    s += __shfl_xor(s, m);
    ss += __shfl_xor(ss, m);
  }
  int w = tid >> 6;
  if ((tid & 63) == 0) { red[w] = s; red[4 + w] = ss; }
  __syncthreads();
  s = red[0] + red[1] + red[2] + red[3];
  ss = red[4] + red[5] + red[6] + red[7];
  float mu = s * (1.0f / 512.0f);
  float var = ss * (1.0f / 512.0f) - mu * mu;
  float rstd = 1.0f / sqrtf(var + 1e-6f);
  float y0 = (x0 - mu) * rstd * gg[tid] + bb[tid];
  float y1 = (x1 - mu) * rstd * gg[tid + 256] + bb[tid + 256];
  if (outF) { outF[base + tid] = y0; outF[base + tid + 256] = y1; }
  if (outB) { outB[base + tid] = f2bf(y0); outB[base + tid + 256] = f2bf(y1); }
}

// ---------------- host orchestration ----------------
extern "C" void kernel_launch(void* const* d_in, const int* in_sizes, int n_in,
                              void* d_out, int out_size, void* d_ws, size_t ws_size,
                              hipStream_t stream) {
  const float* S      = (const float*)d_in[0];
  const int*   maskp  = (const int*)d_in[1];
  const float* ca_wq  = (const float*)d_in[3];
  const float* ca_bq  = (const float*)d_in[4];
  const float* ca_wk  = (const float*)d_in[5];
  const float* ca_bk  = (const float*)d_in[6];
  const float* ca_wv  = (const float*)d_in[7];
  const float* ca_bv  = (const float*)d_in[8];
  const float* ca_wo  = (const float*)d_in[9];
  const float* ca_bo  = (const float*)d_in[10];
  const float* ia_wq  = (const float*)d_in[11];
  const float* ia_bq  = (const float*)d_in[12];
  const float* ia_wk  = (const float*)d_in[13];
  const float* ia_bk  = (const float*)d_in[14];
  const float* ia_wv  = (const float*)d_in[15];
  const float* ia_bv  = (const float*)d_in[16];
  const float* ia_wo  = (const float*)d_in[17];
  const float* ia_bo  = (const float*)d_in[18];
  const float* ffn_w1 = (const float*)d_in[19];
  const float* ffn_b1 = (const float*)d_in[20];
  const float* ffn_w2 = (const float*)d_in[21];
  const float* ffn_b2 = (const float*)d_in[22];
  const float* ln1_g  = (const float*)d_in[23];
  const float* ln1_b  = (const float*)d_in[24];
  const float* ln2_g  = (const float*)d_in[25];
  const float* ln2_b  = (const float*)d_in[26];

  char* ws = (char*)d_ws;
  constexpr size_t OFF_WQT  = 0;
  constexpr size_t OFF_WOTC = 2097152;
  constexpr size_t OFF_WVTI = 2621440;
  constexpr size_t OFF_WOTI = 3145728;
  constexpr size_t OFF_W1T  = 3670016;
  constexpr size_t OFF_W2T  = 5767168;
  constexpr size_t OFF_QC   = 7864320;
  constexpr size_t OFF_KC   = 11010048;
  constexpr size_t OFF_VT   = 14155776;
  constexpr size_t OFF_QI   = 17301504;
  constexpr size_t OFF_AC   = 20447232;
  constexpr size_t OFF_S2   = 70778880;
  constexpr size_t OFF_UBIG = 121110528;
  constexpr size_t NEED_BIG = OFF_UBIG + 25165824;
  constexpr size_t OFF_SB   = OFF_AC;
  constexpr size_t OFF_Y    = OFF_AC + 25165824;
  constexpr size_t OFF_AO   = OFF_QI;
  constexpr size_t OFF_IAO  = OFF_QC;           // 2 parts x 6291456 B
  constexpr size_t OFF_SNF  = OFF_S2;
  constexpr size_t OFF_SNB  = OFF_VT + 6291456;
  constexpr size_t OFF_HFF  = OFF_S2 + 6291456;
  constexpr size_t OFF_FFO  = OFF_HFF + 12582912; // 2 parts x 6291456 B

  u16* wqT  = (u16*)(ws + OFF_WQT);
  u16* woTc = (u16*)(ws + OFF_WOTC);
  u16* wvTi = (u16*)(ws + OFF_WVTI);
  u16* woTi = (u16*)(ws + OFF_WOTI);
  u16* w1T  = (u16*)(ws + OFF_W1T);
  u16* w2T  = (u16*)(ws + OFF_W2T);
  u16* Qc   = (u16*)(ws + OFF_QC);
  u16* Kc   = (u16*)(ws + OFF_KC);
  u16* Vt   = (u16*)(ws + OFF_VT);
  u16* Qi   = (u16*)(ws + OFF_QI);
  u16* AC   = (u16*)(ws + OFF_AC);
  u16* Sb   = (u16*)(ws + OFF_SB);
  u16* S2   = (u16*)(ws + OFF_S2);
  u16* Y    = (u16*)(ws + OFF_Y);
  u16* AO   = (u16*)(ws + OFF_AO);
  float* IAO = (float*)(ws + OFF_IAO);
  float* SNF = (float*)(ws + OFF_SNF);
  u16* SNB  = (u16*)(ws + OFF_SNB);
  u16* HFF  = (u16*)(ws + OFF_HFF);
  float* FFO = (float*)(ws + OFF_FFO);

  bool bigws = ws_size >= NEED_BIG;
  u16* U = bigws ? (u16*)(ws + OFF_UBIG) : (u16*)(ws + OFF_AC);

  static bool attrDone = false;
  if (!attrDone) {
    (void)hipFuncSetAttribute(reinterpret_cast<const void*>(&k_oproj8),
                              hipFuncAttributeMaxDynamicSharedMemorySize, 131072);
    attrDone = true;
  }

  TJobs tj;
  int t0 = 0;
  auto SET = [&](int k, const float* s, u16* d, int R, int C) {
    tj.j[k].src = s; tj.j[k].dst = d; tj.j[k].R = R; tj.j[k].C = C; tj.j[k].tile0 = t0;
    t0 += (R / 32) * (C / 32);
  };
  SET(0, ca_wq, wqT, 512, 512);
  SET(1, ca_wk, wqT + 262144, 512, 512);
  SET(2, ca_wv, wqT + 524288, 512, 512);
  SET(3, ia_wq, wqT + 786432, 512, 512);
  SET(4, ca_wo, woTc, 512, 512);
  SET(5, ia_wv, wvTi, 512, 512);
  SET(6, ia_wo, woTi, 512, 512);
  SET(7, ffn_w1, w1T, 512, 2048);
  SET(8, ffn_w2, w2T, 2048, 512);

  k_prep<<<dim3(768 + t0), 256, 0, stream>>>(S, Sb, tj);
  k_qkv<<<dim3(384), 256, 0, stream>>>(Sb, wqT, ca_bq, ca_bk, ca_bv, ia_bq,
                                       Qc, Kc, Vt, Qi);
  if (bigws) {
    k_attn_up<<<dim3(1792), 256, 0, stream>>>(Qc, Kc, Vt, maskp, AC, Qi, ia_wk,
                                              U, 1024);
    k_oproj8<<<dim3(384), 512, 131072, stream>>>(AC, woTc, ca_bo, S2);
  } else {
    k_attn_up<<<dim3(1024), 256, 0, stream>>>(Qc, Kc, Vt, maskp, AC, Qi, ia_wk,
                                              U, 1024);
    k_oproj8<<<dim3(384), 512, 131072, stream>>>(AC, woTc, ca_bo, S2);
    k_attn_up<<<dim3(768), 256, 0, stream>>>(Qc, Kc, Vt, maskp, AC, Qi, ia_wk,
                                             U, 0);
  }
  k_ia_attn<<<dim3(3072), 256, 0, stream>>>(S2, U, Qi, ia_bk, Y);
  k_vapply<<<dim3(24, 1, 8), 256, 0, stream>>>(Y, wvTi, ia_bv, AO);
  k_gemm_f32out<<<dim3(192, 2), 256, 0, stream>>>(AO, 512, woTi, ia_bo, IAO);
  k_ln<<<dim3(3072), 256, 0, stream>>>(S, IAO, IAO + 3072 * 512, ln1_g, ln1_b,
                                       SNF, SNB);
  k_ffn1<<<dim3(384), 256, 0, stream>>>(SNB, w1T, ffn_b1, HFF);
  k_gemm_f32out<<<dim3(192, 2), 256, 0, stream>>>(HFF, 2048, w2T, ffn_b2, FFO);
  k_ln<<<dim3(3072), 256, 0, stream>>>(SNF, FFO, FFO + 3072 * 512, ln2_g, ln2_b,
                                       (float*)d_out, nullptr);
}

// Round 14
// 200.619 us; speedup vs baseline: 1.0353x; 1.0353x over previous
//
#include <hip/hip_runtime.h>

// CrossTransformerLayer on MI355X — round 14 = exact round-12 restoration
// (best measured: 200.5us). r13's i-chunk attn regressed (VGPR 72->96, occ
// 18%, FETCH 3x); reverted. Locked: attn = (pair,head) block, K+V both
// LDS-staged, 49.9KB; prep fusion; split-K=2 f32-out GEMMs; oproj8 8-phase.

using u16 = unsigned short;
using u32 = unsigned int;
typedef __attribute__((ext_vector_type(8))) short short8;
typedef __attribute__((ext_vector_type(4))) float f32x4;

__device__ __forceinline__ u32 cvtpk(float lo, float hi) {
  u32 r;
  asm("v_cvt_pk_bf16_f32 %0, %1, %2" : "=v"(r) : "v"(lo), "v"(hi));
  return r;
}
__device__ __forceinline__ u16 f2bf(float f) { return (u16)cvtpk(f, f); }
__device__ __forceinline__ float bf2f(u16 h) {
  return __uint_as_float(((u32)h) << 16);
}
__device__ __forceinline__ float exp2a(float x) {
  float r;
  asm("v_exp_f32 %0, %1" : "=v"(r) : "v"(x));
  return r;
}
__device__ __forceinline__ f32x4 mfma16(short8 a, short8 b, f32x4 c) {
  return __builtin_amdgcn_mfma_f32_16x16x32_bf16(a, b, c, 0, 0, 0);
}
__device__ __forceinline__ void gload16(const void* g, u16* l) {
  __builtin_amdgcn_global_load_lds(
      (const __attribute__((address_space(1))) void*)g,
      (__attribute__((address_space(3))) void*)l, 16, 0, 0);
}

// ---------------- staging (BK=64 cols, row stride 64 elems, 16B-slot swizzle) ----
template<int ROWS, int NT>
__device__ __forceinline__ void stage_g16(u16* lds, const u16* __restrict__ src,
                                          int ld, int tid) {
  constexpr int UNITS = ROWS * 8;
  constexpr int WV = NT / 64;
  int lane = tid & 63, w = tid >> 6;
  #pragma unroll
  for (int u = 0; u < UNITS / NT; ++u) {
    int base = (u * WV + w) * 64;
    int unit = base + lane;
    int row = unit >> 3, co = unit & 7;
    gload16(src + (long)row * ld + ((co ^ (row & 7)) << 3), lds + base * 8);
  }
}
template<int ROWS, int NT>
__device__ __forceinline__ void stage_f32(u16* lds, const float* __restrict__ src,
                                          int ld, int tid) {
  constexpr int UNITS = ROWS * 8;
  #pragma unroll
  for (int u = 0; u < UNITS / NT; ++u) {
    int unit = tid + u * NT;
    int row = unit >> 3, co = unit & 7;
    const float* g = src + (long)row * ld + (co << 3);
    float4 a = *(const float4*)g;
    float4 b = *(const float4*)(g + 4);
    u32 p[4] = {cvtpk(a.x, a.y), cvtpk(a.z, a.w),
                cvtpk(b.x, b.y), cvtpk(b.z, b.w)};
    *(uint4*)&lds[(row << 6) + ((co ^ (row & 7)) << 3)] = *(const uint4*)p;
  }
}

// ---------------- generic GEMM core: D = A @ B^T (1-phase, small shapes) ------
template<typename AT, typename BT, int BM, int BN, int WM, int WN>
__device__ __forceinline__ void gemm_core(const AT* __restrict__ A, int lda,
                                          const BT* __restrict__ Bt, int ldb, int K,
                                          u16* As, u16* Bs,
                                          f32x4 (&acc)[BM / (WM * 16)][BN / (WN * 16)]) {
  constexpr int NT = WM * WN * 64;
  constexpr int MI = BM / (WM * 16), NJ = BN / (WN * 16);
  int tid = threadIdx.x, lane = tid & 63, wid = tid >> 6;
  int wr = wid % WM, wc = wid / WM;
  int g = lane >> 4, c = lane & 15;
  #pragma unroll
  for (int mi = 0; mi < MI; ++mi)
    #pragma unroll
    for (int nj = 0; nj < NJ; ++nj)
      acc[mi][nj] = f32x4{0.f, 0.f, 0.f, 0.f};
  for (int kb = 0; kb < K; kb += 64) {
    __syncthreads();
    if constexpr (sizeof(AT) == 4) stage_f32<BM, NT>(As, A + kb, lda, tid);
    else                           stage_g16<BM, NT>(As, A + kb, lda, tid);
    if constexpr (sizeof(BT) == 4) stage_f32<BN, NT>(Bs, Bt + kb, ldb, tid);
    else                           stage_g16<BN, NT>(Bs, Bt + kb, ldb, tid);
    __syncthreads();
    #pragma unroll
    for (int kk = 0; kk < 2; ++kk) {
      int sl = ((kk * 4 + g) ^ (c & 7)) << 3;
      short8 af[MI], bfr[NJ];
      #pragma unroll
      for (int mi = 0; mi < MI; ++mi)
        af[mi] = *(const short8*)&As[((wr * (BM / WM) + mi * 16 + c) << 6) + sl];
      #pragma unroll
      for (int nj = 0; nj < NJ; ++nj)
        bfr[nj] = *(const short8*)&Bs[((wc * (BN / WN) + nj * 16 + c) << 6) + sl];
      #pragma unroll
      for (int mi = 0; mi < MI; ++mi)
        #pragma unroll
        for (int nj = 0; nj < NJ; ++nj)
          acc[mi][nj] = mfma16(af[mi], bfr[nj], acc[mi][nj]);
    }
  }
}

// ---------------- fused prep: S cast (768 blocks) + weight transpose ----------
struct TJob { const float* src; u16* dst; int R, C, tile0; };
struct TJobs { TJob j[9]; };

__global__ __launch_bounds__(256) void k_prep(const float* __restrict__ S,
                                              u16* __restrict__ Sb, TJobs jobs) {
  __shared__ float tile[32][33];
  int bid = blockIdx.x;
  if (bid < 768) {  // cast S fp32 -> bf16
    int idx = (bid * 256 + threadIdx.x) * 8;
    float4 a = *(const float4*)(S + idx);
    float4 b = *(const float4*)(S + idx + 4);
    u32 p[4] = {cvtpk(a.x, a.y), cvtpk(a.z, a.w),
                cvtpk(b.x, b.y), cvtpk(b.z, b.w)};
    *(uint4*)(Sb + idx) = *(const uint4*)p;
    return;
  }
  int t = bid - 768;
  int ji = 0;
  #pragma unroll
  for (int k = 1; k < 9; ++k)
    if (t >= jobs.j[k].tile0) ji = k;
  TJob jb = jobs.j[ji];
  int lt = t - jb.tile0;
  int tpr = jb.C >> 5;
  int tr = lt / tpr, tc = lt % tpr;
  int tid = threadIdx.x;
  #pragma unroll
  for (int u = 0; u < 4; ++u) {
    int e = tid + u * 256;
    int r = e >> 5, cc = e & 31;
    tile[r][cc] = jb.src[(long)(tr * 32 + r) * jb.C + tc * 32 + cc];
  }
  __syncthreads();
  #pragma unroll
  for (int u = 0; u < 4; ++u) {
    int e = tid + u * 256;
    int r = e >> 5, cc = e & 31;
    jb.dst[(long)(tc * 32 + r) * jb.R + tr * 32 + cc] = f2bf(tile[cc][r]);
  }
}

// ---------------- G1: unified QKV+iaQ projection (bf16 GEMM, N=2048) ----------
__global__ __launch_bounds__(256) void k_qkv(const u16* __restrict__ Sb,
    const u16* __restrict__ btAll,
    const float* __restrict__ b0, const float* __restrict__ b1,
    const float* __restrict__ b2, const float* __restrict__ b3,
    u16* __restrict__ Qc, u16* __restrict__ Kc, u16* __restrict__ Vt,
    u16* __restrict__ Qi) {
  __shared__ u16 SH[16384];
  int f = blockIdx.x;                       // 384 blocks
  int swz = (f & 7) * 48 + (f >> 3);
  int mb = swz >> 4, nb = swz & 15;
  f32x4 acc[4][4];
  gemm_core<u16, u16, 128, 128, 2, 2>(Sb + (long)mb * 128 * 512, 512,
                                      btAll + (long)nb * 128 * 512, 512, 512,
                                      SH, SH + 8192, acc);
  int z = nb >> 2;
  const float* bias = z == 0 ? b0 : z == 1 ? b1 : z == 2 ? b2 : b3;
  // z==0: Qc scaled by 1/8 * log2(e) so CA softmax can use exp2 directly.
  float scale = z == 0 ? 0.18033688011112042f : (z == 3 ? 0.125f : 1.0f);
  int lane = threadIdx.x & 63, wid = threadIdx.x >> 6;
  int wr = wid & 1, wc = wid >> 1, g = lane >> 4, cl = lane & 15;
  #pragma unroll
  for (int mi = 0; mi < 4; ++mi)
    #pragma unroll
    for (int nj = 0; nj < 4; ++nj)
      #pragma unroll
      for (int r = 0; r < 4; ++r) {
        int row = mb * 128 + wr * 64 + mi * 16 + g * 4 + r;
        int cz = (nb & 3) * 128 + wc * 64 + nj * 16 + cl;
        float v = (acc[mi][nj][r] + bias[cz]) * scale;
        int seq = row / 192, t = row % 192, h = cz >> 6, hd = cz & 63;
        if (z == 0)      Qc[((long)(seq * 8 + h) * 192 + t) * 64 + hd] = f2bf(v);
        else if (z == 1) Kc[((long)(seq * 8 + h) * 192 + t) * 64 + hd] = f2bf(v);
        else if (z == 2) Vt[((long)(seq * 8 + h) * 64 + hd) * 192 + t] = f2bf(v);
        else             Qi[(long)row * 512 + cz] = f2bf(v);
      }
}

// ---------------- G2: CA attention (staged K/V) + uproj tail, one dispatch ----
__global__ __launch_bounds__(256) void k_attn_up(const u16* __restrict__ Qc,
    const u16* __restrict__ Kc, const u16* __restrict__ VtG,
    const int* __restrict__ mask, u16* __restrict__ AC,
    const u16* __restrict__ Qi, const float* __restrict__ wk,
    u16* __restrict__ U, int attnBlocks) {
  __shared__ __align__(16) u16 SH[24960];
  int bid = blockIdx.x;
  int tid = threadIdx.x, lane = tid & 63, w = tid >> 6;
  int g = lane >> 4, c = lane & 15;
  if (bid < attnBlocks) {
    u16* Ks = SH;
    u16* Vs = SH + 12288;
    float* mbf = (float*)(SH + 24576);
    int b = bid >> 3, h = bid & 7;
    int i = b >> 4, j = b & 15;
    int qb = w * 48;

    const u16* Kbase = Kc + (long)(j * 8 + h) * 192 * 64;
    #pragma unroll
    for (int u = 0; u < 6; ++u) {
      int base = (u * 4 + w) * 64;
      int unit = base + lane;
      int row = unit >> 3, co = unit & 7;
      gload16(Kbase + (long)row * 64 + ((co ^ (row & 7)) << 3), Ks + base * 8);
    }
    const u16* Vbase = VtG + (long)(j * 8 + h) * 64 * 192;
    #pragma unroll
    for (int u = 0; u < 6; ++u) {
      int base = (u * 4 + w) * 64;
      int unit = base + lane;
      int row = unit / 24, co = unit - row * 24;
      gload16(Vbase + (long)row * 192 + ((co ^ (row & 7)) << 3), Vs + base * 8);
    }
    short8 bq[3][2];
    const u16* Qbase = Qc + (long)(i * 8 + h) * 192 * 64;
    #pragma unroll
    for (int nj = 0; nj < 3; ++nj)
      #pragma unroll
      for (int ks = 0; ks < 2; ++ks)
        bq[nj][ks] = *(const short8*)(Qbase + (long)(qb + nj * 16 + c) * 64 + ks * 32 + g * 8);
    if (tid < 192) mbf[tid] = mask[(long)b * 192 + tid] ? 0.f : -1e9f;
    __syncthreads();

    f32x4 oa[4][3];
    #pragma unroll
    for (int mi = 0; mi < 4; ++mi)
      #pragma unroll
      for (int nj = 0; nj < 3; ++nj)
        oa[mi][nj] = f32x4{0.f, 0.f, 0.f, 0.f};
    float sm[3] = {0.f, 0.f, 0.f};
    int srcLo = c | ((g & 1) << 5);
    int srcHi = srcLo + 16;
    int hi = g & 2;

    for (int s = 0; s < 6; ++s) {
      short8 ak[2][2];
      #pragma unroll
      for (int kh = 0; kh < 2; ++kh) {
        int row = (2 * s + kh) * 16 + c;
        #pragma unroll
        for (int ks = 0; ks < 2; ++ks)
          ak[kh][ks] = *(const short8*)&Ks[(row << 6) + (((ks * 4 + g) ^ (c & 7)) << 3)];
      }
      f32x4 sa[2][3];
      __builtin_amdgcn_s_setprio(1);
      #pragma unroll
      for (int kh = 0; kh < 2; ++kh)
        #pragma unroll
        for (int nj = 0; nj < 3; ++nj) {
          sa[kh][nj] = mfma16(ak[kh][0], bq[nj][0], f32x4{0.f, 0.f, 0.f, 0.f});
          sa[kh][nj] = mfma16(ak[kh][1], bq[nj][1], sa[kh][nj]);
        }
      __builtin_amdgcn_s_setprio(0);
      u32 pk[2][3][2];
      #pragma unroll
      for (int kh = 0; kh < 2; ++kh) {
        f32x4 m4 = *(const f32x4*)&mbf[(2 * s + kh) * 16 + g * 4];
        #pragma unroll
        for (int nj = 0; nj < 3; ++nj) {
          float p0 = exp2a(sa[kh][nj][0] + m4[0]);
          float p1 = exp2a(sa[kh][nj][1] + m4[1]);
          float p2 = exp2a(sa[kh][nj][2] + m4[2]);
          float p3 = exp2a(sa[kh][nj][3] + m4[3]);
          sm[nj] += (p0 + p1) + (p2 + p3);
          pk[kh][nj][0] = cvtpk(p0, p1);
          pk[kh][nj][1] = cvtpk(p2, p3);
        }
      }
      short8 bfg[3];
      #pragma unroll
      for (int nj = 0; nj < 3; ++nj) {
        u32 w0a = (u32)__shfl((int)pk[0][nj][0], srcLo);
        u32 w0b = (u32)__shfl((int)pk[1][nj][0], srcLo);
        u32 w1a = (u32)__shfl((int)pk[0][nj][1], srcLo);
        u32 w1b = (u32)__shfl((int)pk[1][nj][1], srcLo);
        u32 w2a = (u32)__shfl((int)pk[0][nj][0], srcHi);
        u32 w2b = (u32)__shfl((int)pk[1][nj][0], srcHi);
        u32 w3a = (u32)__shfl((int)pk[0][nj][1], srcHi);
        u32 w3b = (u32)__shfl((int)pk[1][nj][1], srcHi);
        union { u32 u[4]; short8 s8; } bf;
        bf.u[0] = hi ? w0b : w0a;
        bf.u[1] = hi ? w1b : w1a;
        bf.u[2] = hi ? w2b : w2a;
        bf.u[3] = hi ? w3b : w3a;
        bfg[nj] = bf.s8;
      }
      int sl = ((s * 4 + g) ^ (c & 7)) << 3;
      __builtin_amdgcn_s_setprio(1);
      #pragma unroll
      for (int mi = 0; mi < 4; ++mi) {
        short8 av = *(const short8*)&Vs[(mi * 16 + c) * 192 + sl];
        #pragma unroll
        for (int nj = 0; nj < 3; ++nj)
          oa[mi][nj] = mfma16(av, bfg[nj], oa[mi][nj]);
      }
      __builtin_amdgcn_s_setprio(0);
    }
    #pragma unroll
    for (int nj = 0; nj < 3; ++nj) {
      sm[nj] += __shfl_xor(sm[nj], 16);
      sm[nj] += __shfl_xor(sm[nj], 32);
    }
    #pragma unroll
    for (int nj = 0; nj < 3; ++nj) {
      float rs = 1.0f / sm[nj];
      int q = qb + nj * 16 + c;
      u16* dst = AC + ((long)(b * 192 + q)) * 512 + h * 64 + g * 4;
      #pragma unroll
      for (int mi = 0; mi < 4; ++mi) {
        u32 p2[2] = {cvtpk(oa[mi][nj][0] * rs, oa[mi][nj][1] * rs),
                     cvtpk(oa[mi][nj][2] * rs, oa[mi][nj][3] * rs)};
        *(uint2*)(dst + mi * 16) = *(const uint2*)p2;
      }
    }
  } else {
    u16* As = SH;
    u16* Bs = SH + 8192;
    int t = bid - attnBlocks;
    int mb = t % 24, r2 = t / 24;
    int nb = r2 & 3, h = r2 >> 2;
    f32x4 acc[4][4];
    gemm_core<u16, float, 128, 128, 2, 2>(Qi + (long)mb * 128 * 512 + h * 64, 512,
                                          wk + (long)nb * 128 * 512 + h * 64, 512, 64,
                                          As, Bs, acc);
    int wr = w & 1, wc = w >> 1, cl = lane & 15;
    #pragma unroll
    for (int mi = 0; mi < 4; ++mi)
      #pragma unroll
      for (int nj = 0; nj < 4; ++nj)
        #pragma unroll
        for (int r = 0; r < 4; ++r) {
          int row = mb * 128 + wr * 64 + mi * 16 + g * 4 + r;
          int col = nb * 128 + wc * 64 + nj * 16 + cl;
          U[((long)row * 8 + h) * 512 + col] = f2bf(acc[mi][nj][r]);
        }
  }
}

// ---------------- G3: CA out-proj — 256^2 8-phase pipelined GEMM ----------
__global__ __launch_bounds__(512, 1) void k_oproj8(const u16* __restrict__ AC,
    const u16* __restrict__ woT, const float* __restrict__ bo,
    u16* __restrict__ S2) {
  extern __shared__ u16 LDS[];
  int f = blockIdx.x;                       // 384 blocks
  int swz = (f & 7) * 48 + (f >> 3);
  int mb = swz >> 1, nb = swz & 1;
  int tid = threadIdx.x, lane = tid & 63, wid = tid >> 6;
  int wr = wid >> 2, wc = wid & 3;
  int g = lane >> 4, c = lane & 15;
  const u16* Abase = AC + (long)mb * 256 * 512;
  const u16* Bbase = woT + (long)nb * 256 * 512;

  auto STAGE = [&](int opOff, int buf, int half, int kt, const u16* base) {
    u16* ldst = LDS + opOff + buf * 16384 + half * 8192;
    const u16* gsrc = base + (long)half * 128 * 512 + kt * 64;
    #pragma unroll
    for (int u = 0; u < 2; ++u) {
      int unit = tid + u * 512;
      int row = unit >> 3, co = unit & 7;
      gload16(gsrc + (long)row * 512 + ((co ^ (row & 7)) << 3), ldst + unit * 8);
    }
  };

  f32x4 acc[8][4];
  #pragma unroll
  for (int mi = 0; mi < 8; ++mi)
    #pragma unroll
    for (int nj = 0; nj < 4; ++nj)
      acc[mi][nj] = f32x4{0.f, 0.f, 0.f, 0.f};

  STAGE(0, 0, 0, 0, Abase);     STAGE(0, 0, 1, 0, Abase);
  STAGE(32768, 0, 0, 0, Bbase); STAGE(32768, 0, 1, 0, Bbase);
  STAGE(0, 1, 0, 1, Abase);     STAGE(0, 1, 1, 1, Abase);
  STAGE(32768, 1, 0, 1, Bbase); STAGE(32768, 1, 1, 1, Bbase);
  asm volatile("s_waitcnt vmcnt(8)");
  __builtin_amdgcn_s_barrier();

  short8 aLo[8], aHi[8], bLo[4], bHi[4];
  for (int t = 0; t < 8; ++t) {
    int buf = t & 1;
    int abase = buf * 16384, bbase = 32768 + buf * 16384;
    #pragma unroll
    for (int m = 0; m < 4; ++m)
      #pragma unroll
      for (int kk = 0; kk < 2; ++kk)
        aLo[m * 2 + kk] = *(const short8*)&LDS[abase +
            (wr * 128 + m * 16 + c) * 64 + (((kk * 4 + g) ^ (c & 7)) << 3)];
    #pragma unroll
    for (int n = 0; n < 2; ++n)
      #pragma unroll
      for (int kk = 0; kk < 2; ++kk)
        bLo[n * 2 + kk] = *(const short8*)&LDS[bbase +
            (wc * 64 + n * 16 + c) * 64 + (((kk * 4 + g) ^ (c & 7)) << 3)];
    __builtin_amdgcn_s_barrier();
    asm volatile("s_waitcnt lgkmcnt(0)");
    __builtin_amdgcn_sched_barrier(0);
    __builtin_amdgcn_s_setprio(1);
    #pragma unroll
    for (int m = 0; m < 4; ++m)
      #pragma unroll
      for (int n = 0; n < 2; ++n)
        #pragma unroll
        for (int kk = 0; kk < 2; ++kk)
          acc[m][n] = mfma16(aLo[m * 2 + kk], bLo[n * 2 + kk], acc[m][n]);
    __builtin_amdgcn_s_setprio(0);
    __builtin_amdgcn_s_barrier();
    #pragma unroll
    for (int m = 0; m < 4; ++m)
      #pragma unroll
      for (int kk = 0; kk < 2; ++kk)
        aHi[m * 2 + kk] = *(const short8*)&LDS[abase +
            (wr * 128 + (4 + m) * 16 + c) * 64 + (((kk * 4 + g) ^ (c & 7)) << 3)];
    __builtin_amdgcn_s_barrier();
    asm volatile("s_waitcnt lgkmcnt(0)");
    __builtin_amdgcn_sched_barrier(0);
    __builtin_amdgcn_s_setprio(1);
    #pragma unroll
    for (int m = 0; m < 4; ++m)
      #pragma unroll
      for (int n = 0; n < 2; ++n)
        #pragma unroll
        for (int kk = 0; kk < 2; ++kk)
          acc[4 + m][n] = mfma16(aHi[m * 2 + kk], bLo[n * 2 + kk], acc[4 + m][n]);
    __builtin_amdgcn_s_setprio(0);
    __builtin_amdgcn_s_barrier();
    #pragma unroll
    for (int n = 0; n < 2; ++n)
      #pragma unroll
      for (int kk = 0; kk < 2; ++kk)
        bHi[n * 2 + kk] = *(const short8*)&LDS[bbase +
            (wc * 64 + (2 + n) * 16 + c) * 64 + (((kk * 4 + g) ^ (c & 7)) << 3)];
    if (t < 6) {
      STAGE(0, buf, 0, t + 2, Abase);
      STAGE(0, buf, 1, t + 2, Abase);
    }
    __builtin_amdgcn_s_barrier();
    asm volatile("s_waitcnt lgkmcnt(0)");
    __builtin_amdgcn_sched_barrier(0);
    __builtin_amdgcn_s_setprio(1);
    #pragma unroll
    for (int m = 0; m < 4; ++m)
      #pragma unroll
      for (int n = 0; n < 2; ++n)
        #pragma unroll
        for (int kk = 0; kk < 2; ++kk)
          acc[m][2 + n] = mfma16(aLo[m * 2 + kk], bHi[n * 2 + kk], acc[m][2 + n]);
    __builtin_amdgcn_s_setprio(0);
    __builtin_amdgcn_s_barrier();
    if (t < 6) {
      STAGE(32768, buf, 0, t + 2, Bbase);
      STAGE(32768, buf, 1, t + 2, Bbase);
    }
    __builtin_amdgcn_s_setprio(1);
    #pragma unroll
    for (int m = 0; m < 4; ++m)
      #pragma unroll
      for (int n = 0; n < 2; ++n)
        #pragma unroll
        for (int kk = 0; kk < 2; ++kk)
          acc[4 + m][2 + n] = mfma16(aHi[m * 2 + kk], bHi[n * 2 + kk], acc[4 + m][2 + n]);
    __builtin_amdgcn_s_setprio(0);
    if (t < 6)      asm volatile("s_waitcnt vmcnt(8)");
    else if (t == 6) asm volatile("s_waitcnt vmcnt(0)");
    if (t < 7) __builtin_amdgcn_s_barrier();
  }
  #pragma unroll
  for (int nj = 0; nj < 4; ++nj) {
    int col = nb * 256 + wc * 64 + nj * 16 + c;
    float bv = bo[col];
    #pragma unroll
    for (int mi = 0; mi < 8; ++mi)
      #pragma unroll
      for (int r = 0; r < 4; ++r) {
        int row = mb * 256 + wr * 128 + mi * 16 + g * 4 + r;
        S2[(long)row * 512 + col] = f2bf(acc[mi][nj][r] + bv);
      }
  }
}

// ---------------- G5: IA attention (MFMA logits + softmax + weighted-sum) -----
__global__ __launch_bounds__(256) void k_ia_attn(const u16* __restrict__ S2,
    const u16* __restrict__ U, const u16* __restrict__ Qi,
    const float* __restrict__ bk, u16* __restrict__ Y) {
  __shared__ u16 s2[16 * 520];
  __shared__ float Lp[4][16][17];
  __shared__ float aL[8][16];
  __shared__ float cL[8];
  int tok = blockIdx.x;
  int tid = threadIdx.x, lane = tid & 63, w = tid >> 6;
  {
    const u16* src = S2 + (long)tok * 512;
    #pragma unroll
    for (int u = 0; u < 4; ++u) {
      int e = tid + u * 256;
      int r = e >> 6, cc = (e & 63) << 3;
      *(uint4*)&s2[r * 520 + cc] = *(const uint4*)(src + (long)r * 3072 * 512 + cc);
    }
  }
  if (w == 0) {
    int h = lane >> 3, p = lane & 7;
    short8 qv = *(const short8*)(Qi + (long)tok * 512 + h * 64 + p * 8);
    const float* bkp = bk + h * 64 + p * 8;
    float s = 0.f;
    #pragma unroll
    for (int v = 0; v < 8; ++v) s += bf2f((u16)qv[v]) * bkp[v];
    s += __shfl_xor(s, 1); s += __shfl_xor(s, 2); s += __shfl_xor(s, 4);
    if (p == 0) cL[h] = s;
  }
  __syncthreads();
  {
    int g = lane >> 4, c = lane & 15;
    const u16* Ub = U + (long)tok * 4096 + (long)(c & 7) * 512;
    f32x4 accL = {0.f, 0.f, 0.f, 0.f};
    #pragma unroll
    for (int kk = 0; kk < 4; ++kk) {
      int d = w * 128 + kk * 32 + g * 8;
      short8 aS = *(const short8*)&s2[c * 520 + d];
      short8 bU = *(const short8*)(Ub + d);
      accL = mfma16(aS, bU, accL);
    }
    #pragma unroll
    for (int r = 0; r < 4; ++r) Lp[w][g * 4 + r][c] = accL[r];
  }
  __syncthreads();
  if (w == 0) {
    int h = lane & 7, i0 = lane >> 3;
    float L0 = Lp[0][i0][h] + Lp[1][i0][h] + Lp[2][i0][h] + Lp[3][i0][h] + cL[h];
    float L1 = Lp[0][i0 + 8][h] + Lp[1][i0 + 8][h] + Lp[2][i0 + 8][h] +
               Lp[3][i0 + 8][h] + cL[h];
    float e0 = __expf(L0), e1 = __expf(L1);
    float s = e0 + e1;
    s += __shfl_xor(s, 8); s += __shfl_xor(s, 16); s += __shfl_xor(s, 32);
    float rs = 1.0f / s;
    aL[h][i0] = e0 * rs;
    aL[h][i0 + 8] = e1 * rs;
  }
  __syncthreads();
  {
    int h = tid & 7, d0 = (tid >> 3) << 4;
    float y[16];
    #pragma unroll
    for (int v = 0; v < 16; ++v) y[v] = 0.f;
    #pragma unroll
    for (int i = 0; i < 16; ++i) {
      float a = aL[h][i];
      short8 v0 = *(const short8*)&s2[i * 520 + d0];
      short8 v1 = *(const short8*)&s2[i * 520 + d0 + 8];
      #pragma unroll
      for (int v = 0; v < 8; ++v) {
        y[v]     += a * bf2f((u16)v0[v]);
        y[8 + v] += a * bf2f((u16)v1[v]);
      }
    }
    u32 o[8];
    #pragma unroll
    for (int v = 0; v < 8; ++v) o[v] = cvtpk(y[2 * v], y[2 * v + 1]);
    u16* dst = Y + ((long)tok * 8 + h) * 512 + d0;
    *(uint4*)dst = *(const uint4*)&o[0];
    *(uint4*)(dst + 8) = *(const uint4*)&o[4];
  }
}

// ---------------- G6: attn_h = y_h @ Wv_h + bv ----------------
__global__ __launch_bounds__(256) void k_vapply(const u16* __restrict__ Y,
    const u16* __restrict__ wvT, const float* __restrict__ bv,
    u16* __restrict__ AO) {
  __shared__ u16 As[128 * 64];
  __shared__ u16 Bs[64 * 64];
  int mb = blockIdx.x, h = blockIdx.z;
  f32x4 acc[2][4];
  gemm_core<u16, u16, 128, 64, 4, 1>(Y + (long)mb * 128 * 4096 + h * 512, 4096,
                                     wvT + (long)h * 64 * 512, 512, 512,
                                     As, Bs, acc);
  int lane = threadIdx.x & 63, wid = threadIdx.x >> 6;
  int g = lane >> 4, cl = lane & 15;
  #pragma unroll
  for (int mi = 0; mi < 2; ++mi)
    #pragma unroll
    for (int nj = 0; nj < 4; ++nj)
      #pragma unroll
      for (int r = 0; r < 4; ++r) {
        int row = mb * 128 + wid * 32 + mi * 16 + g * 4 + r;
        int col = h * 64 + nj * 16 + cl;
        AO[(long)row * 512 + col] = f2bf(acc[mi][nj][r] + bv[col]);
      }
}

// ---------------- generic [3072,K]@[K,512] -> fp32, split-K=2 over grid.y -----
__global__ __launch_bounds__(256) void k_gemm_f32out(const u16* __restrict__ A, int K,
    const u16* __restrict__ BT, const float* __restrict__ bias,
    float* __restrict__ out) {
  __shared__ u16 As[128 * 64];
  __shared__ u16 Bs[64 * 64];
  int f = blockIdx.x;                       // 192 blocks per part
  int ks = blockIdx.y;
  int swz = (f & 7) * 24 + (f >> 3);
  int mb = swz >> 3, nb = swz & 7;
  int Kh = K >> 1;
  f32x4 acc[4][2];
  gemm_core<u16, u16, 128, 64, 2, 2>(A + (long)mb * 128 * K + (long)ks * Kh, K,
                                     BT + (long)nb * 64 * K + (long)ks * Kh, K,
                                     Kh, As, Bs, acc);
  out += (long)ks * 3072 * 512;
  int lane = threadIdx.x & 63, wid = threadIdx.x >> 6;
  int wr = wid & 1, wc = wid >> 1, g = lane >> 4, cl = lane & 15;
  #pragma unroll
  for (int mi = 0; mi < 4; ++mi)
    #pragma unroll
    for (int nj = 0; nj < 2; ++nj)
      #pragma unroll
      for (int r = 0; r < 4; ++r) {
        int row = mb * 128 + wr * 64 + mi * 16 + g * 4 + r;
        int col = nb * 64 + wc * 32 + nj * 16 + cl;
        float bv = ks == 0 ? bias[col] : 0.f;
        out[(long)row * 512 + col] = acc[mi][nj][r] + bv;
      }
}

// ---------------- G9: FFN1 with ReLU -> bf16 (XCD swizzle) ----------------
__global__ __launch_bounds__(256) void k_ffn1(const u16* __restrict__ A,
    const u16* __restrict__ BT, const float* __restrict__ bias,
    u16* __restrict__ out) {
  __shared__ u16 As[128 * 64];
  __shared__ u16 Bs[128 * 64];
  int f = blockIdx.x;                       // 384 blocks
  int swz = (f & 7) * 48 + (f >> 3);
  int mb = swz >> 4, nb = swz & 15;
  f32x4 acc[4][4];
  gemm_core<u16, u16, 128, 128, 2, 2>(A + (long)mb * 128 * 512, 512,
                                      BT + (long)nb * 128 * 512, 512, 512,
                                      As, Bs, acc);
  int lane = threadIdx.x & 63, wid = threadIdx.x >> 6;
  int wr = wid & 1, wc = wid >> 1, g = lane >> 4, cl = lane & 15;
  #pragma unroll
  for (int mi = 0; mi < 4; ++mi)
    #pragma unroll
    for (int nj = 0; nj < 4; ++nj)
      #pragma unroll
      for (int r = 0; r < 4; ++r) {
        int row = mb * 128 + wr * 64 + mi * 16 + g * 4 + r;
        int col = nb * 128 + wc * 64 + nj * 16 + cl;
        out[(long)row * 2048 + col] = f2bf(fmaxf(acc[mi][nj][r] + bias[col], 0.f));
      }
}

// ---------------- LayerNorm over D=512 of (X1+X2[+X3]) ----------------
__global__ __launch_bounds__(256) void k_ln(const float* __restrict__ X1,
    const float* __restrict__ X2, const float* __restrict__ X3,
    const float* __restrict__ gg, const float* __restrict__ bb,
    float* __restrict__ outF, u16* __restrict__ outB) {
  __shared__ float red[8];
  int row = blockIdx.x, tid = threadIdx.x;
  long base = (long)row * 512;
  float x0 = X1[base + tid] + X2[base + tid];
  float x1 = X1[base + tid + 256] + X2[base + tid + 256];
  if (X3) {
    x0 += X3[base + tid];
    x1 += X3[base + tid + 256];
  }
  float s = x0 + x1, ss = x0 * x0 + x1 * x1;
  #pragma unroll
  for (int m = 1; m <= 32; m <<= 1) {
    s += __shfl_xor(s, m);
    ss += __shfl_xor(ss, m);
  }
  int w = tid >> 6;
  if ((tid & 63) == 0) { red[w] = s; red[4 + w] = ss; }
  __syncthreads();
  s = red[0] + red[1] + red[2] + red[3];
  ss = red[4] + red[5] + red[6] + red[7];
  float mu = s * (1.0f / 512.0f);
  float var = ss * (1.0f / 512.0f) - mu * mu;
  float rstd = 1.0f / sqrtf(var + 1e-6f);
  float y0 = (x0 - mu) * rstd * gg[tid] + bb[tid];
  float y1 = (x1 - mu) * rstd * gg[tid + 256] + bb[tid + 256];
  if (outF) { outF[base + tid] = y0; outF[base + tid + 256] = y1; }
  if (outB) { outB[base + tid] = f2bf(y0); outB[base + tid + 256] = f2bf(y1); }
}

// ---------------- host orchestration ----------------
extern "C" void kernel_launch(void* const* d_in, const int* in_sizes, int n_in,
                              void* d_out, int out_size, void* d_ws, size_t ws_size,
                              hipStream_t stream) {
  const float* S      = (const float*)d_in[0];
  const int*   maskp  = (const int*)d_in[1];
  const float* ca_wq  = (const float*)d_in[3];
  const float* ca_bq  = (const float*)d_in[4];
  const float* ca_wk  = (const float*)d_in[5];
  const float* ca_bk  = (const float*)d_in[6];
  const float* ca_wv  = (const float*)d_in[7];
  const float* ca_bv  = (const float*)d_in[8];
  const float* ca_wo  = (const float*)d_in[9];
  const float* ca_bo  = (const float*)d_in[10];
  const float* ia_wq  = (const float*)d_in[11];
  const float* ia_bq  = (const float*)d_in[12];
  const float* ia_wk  = (const float*)d_in[13];
  const float* ia_bk  = (const float*)d_in[14];
  const float* ia_wv  = (const float*)d_in[15];
  const float* ia_bv  = (const float*)d_in[16];
  const float* ia_wo  = (const float*)d_in[17];
  const float* ia_bo  = (const float*)d_in[18];
  const float* ffn_w1 = (const float*)d_in[19];
  const float* ffn_b1 = (const float*)d_in[20];
  const float* ffn_w2 = (const float*)d_in[21];
  const float* ffn_b2 = (const float*)d_in[22];
  const float* ln1_g  = (const float*)d_in[23];
  const float* ln1_b  = (const float*)d_in[24];
  const float* ln2_g  = (const float*)d_in[25];
  const float* ln2_b  = (const float*)d_in[26];

  char* ws = (char*)d_ws;
  constexpr size_t OFF_WQT  = 0;
  constexpr size_t OFF_WOTC = 2097152;
  constexpr size_t OFF_WVTI = 2621440;
  constexpr size_t OFF_WOTI = 3145728;
  constexpr size_t OFF_W1T  = 3670016;
  constexpr size_t OFF_W2T  = 5767168;
  constexpr size_t OFF_QC   = 7864320;
  constexpr size_t OFF_KC   = 11010048;
  constexpr size_t OFF_VT   = 14155776;
  constexpr size_t OFF_QI   = 17301504;
  constexpr size_t OFF_AC   = 20447232;
  constexpr size_t OFF_S2   = 70778880;
  constexpr size_t OFF_UBIG = 121110528;
  constexpr size_t NEED_BIG = OFF_UBIG + 25165824;
  constexpr size_t OFF_SB   = OFF_AC;
  constexpr size_t OFF_Y    = OFF_AC + 25165824;
  constexpr size_t OFF_AO   = OFF_QI;
  constexpr size_t OFF_IAO  = OFF_QC;           // 2 parts x 6291456 B
  constexpr size_t OFF_SNF  = OFF_S2;
  constexpr size_t OFF_SNB  = OFF_VT + 6291456;
  constexpr size_t OFF_HFF  = OFF_S2 + 6291456;
  constexpr size_t OFF_FFO  = OFF_HFF + 12582912; // 2 parts x 6291456 B

  u16* wqT  = (u16*)(ws + OFF_WQT);
  u16* woTc = (u16*)(ws + OFF_WOTC);
  u16* wvTi = (u16*)(ws + OFF_WVTI);
  u16* woTi = (u16*)(ws + OFF_WOTI);
  u16* w1T  = (u16*)(ws + OFF_W1T);
  u16* w2T  = (u16*)(ws + OFF_W2T);
  u16* Qc   = (u16*)(ws + OFF_QC);
  u16* Kc   = (u16*)(ws + OFF_KC);
  u16* Vt   = (u16*)(ws + OFF_VT);
  u16* Qi   = (u16*)(ws + OFF_QI);
  u16* AC   = (u16*)(ws + OFF_AC);
  u16* Sb   = (u16*)(ws + OFF_SB);
  u16* S2   = (u16*)(ws + OFF_S2);
  u16* Y    = (u16*)(ws + OFF_Y);
  u16* AO   = (u16*)(ws + OFF_AO);
  float* IAO = (float*)(ws + OFF_IAO);
  float* SNF = (float*)(ws + OFF_SNF);
  u16* SNB  = (u16*)(ws + OFF_SNB);
  u16* HFF  = (u16*)(ws + OFF_HFF);
  float* FFO = (float*)(ws + OFF_FFO);

  bool bigws = ws_size >= NEED_BIG;
  u16* U = bigws ? (u16*)(ws + OFF_UBIG) : (u16*)(ws + OFF_AC);

  static bool attrDone = false;
  if (!attrDone) {
    (void)hipFuncSetAttribute(reinterpret_cast<const void*>(&k_oproj8),
                              hipFuncAttributeMaxDynamicSharedMemorySize, 131072);
    attrDone = true;
  }

  TJobs tj;
  int t0 = 0;
  auto SET = [&](int k, const float* s, u16* d, int R, int C) {
    tj.j[k].src = s; tj.j[k].dst = d; tj.j[k].R = R; tj.j[k].C = C; tj.j[k].tile0 = t0;
    t0 += (R / 32) * (C / 32);
  };
  SET(0, ca_wq, wqT, 512, 512);
  SET(1, ca_wk, wqT + 262144, 512, 512);
  SET(2, ca_wv, wqT + 524288, 512, 512);
  SET(3, ia_wq, wqT + 786432, 512, 512);
  SET(4, ca_wo, woTc, 512, 512);
  SET(5, ia_wv, wvTi, 512, 512);
  SET(6, ia_wo, woTi, 512, 512);
  SET(7, ffn_w1, w1T, 512, 2048);
  SET(8, ffn_w2, w2T, 2048, 512);

  k_prep<<<dim3(768 + t0), 256, 0, stream>>>(S, Sb, tj);
  k_qkv<<<dim3(384), 256, 0, stream>>>(Sb, wqT, ca_bq, ca_bk, ca_bv, ia_bq,
                                       Qc, Kc, Vt, Qi);
  if (bigws) {
    k_attn_up<<<dim3(2816), 256, 0, stream>>>(Qc, Kc, Vt, maskp, AC, Qi, ia_wk,
                                              U, 2048);
    k_oproj8<<<dim3(384), 512, 131072, stream>>>(AC, woTc, ca_bo, S2);
  } else {
    k_attn_up<<<dim3(2048), 256, 0, stream>>>(Qc, Kc, Vt, maskp, AC, Qi, ia_wk,
                                              U, 2048);
    k_oproj8<<<dim3(384), 512, 131072, stream>>>(AC, woTc, ca_bo, S2);
    k_attn_up<<<dim3(768), 256, 0, stream>>>(Qc, Kc, Vt, maskp, AC, Qi, ia_wk,
                                             U, 0);
  }
  k_ia_attn<<<dim3(3072), 256, 0, stream>>>(S2, U, Qi, ia_bk, Y);
  k_vapply<<<dim3(24, 1, 8), 256, 0, stream>>>(Y, wvTi, ia_bv, AO);
  k_gemm_f32out<<<dim3(192, 2), 256, 0, stream>>>(AO, 512, woTi, ia_bo, IAO);
  k_ln<<<dim3(3072), 256, 0, stream>>>(S, IAO, IAO + 3072 * 512, ln1_g, ln1_b,
                                       SNF, SNB);
  k_ffn1<<<dim3(384), 256, 0, stream>>>(SNB, w1T, ffn_b1, HFF);
  k_gemm_f32out<<<dim3(192, 2), 256, 0, stream>>>(HFF, 2048, w2T, ffn_b2, FFO);
  k_ln<<<dim3(3072), 256, 0, stream>>>(SNF, FFO, FFO + 3072 * 512, ln2_g, ln2_b,
                                       (float*)d_out, nullptr);
}

// Round 15
// 200.035 us; speedup vs baseline: 1.0384x; 1.0029x over previous
//
#include <hip/hip_runtime.h>

// CrossTransformerLayer on MI355X — round 15.
// = round 14 (repro'd best, 200.6us) with ONE change: k_oproj8 retiled
// 256x256 -> 256x128. Old grid: 384 blocks @1/CU = 1.5 ragged rounds (half
// the CUs idle for the 2nd half). New: 768 blocks = exactly 3.0 even rounds.
// Same 4-phase counted-vmcnt schedule (A restaged P3, B restaged P4),
// vmcnt 8->6 (4 A-loads + 2 B-loads per tile in flight). LDS 96KB.

using u16 = unsigned short;
using u32 = unsigned int;
typedef __attribute__((ext_vector_type(8))) short short8;
typedef __attribute__((ext_vector_type(4))) float f32x4;

__device__ __forceinline__ u32 cvtpk(float lo, float hi) {
  u32 r;
  asm("v_cvt_pk_bf16_f32 %0, %1, %2" : "=v"(r) : "v"(lo), "v"(hi));
  return r;
}
__device__ __forceinline__ u16 f2bf(float f) { return (u16)cvtpk(f, f); }
__device__ __forceinline__ float bf2f(u16 h) {
  return __uint_as_float(((u32)h) << 16);
}
__device__ __forceinline__ float exp2a(float x) {
  float r;
  asm("v_exp_f32 %0, %1" : "=v"(r) : "v"(x));
  return r;
}
__device__ __forceinline__ f32x4 mfma16(short8 a, short8 b, f32x4 c) {
  return __builtin_amdgcn_mfma_f32_16x16x32_bf16(a, b, c, 0, 0, 0);
}
__device__ __forceinline__ void gload16(const void* g, u16* l) {
  __builtin_amdgcn_global_load_lds(
      (const __attribute__((address_space(1))) void*)g,
      (__attribute__((address_space(3))) void*)l, 16, 0, 0);
}

// ---------------- staging (BK=64 cols, row stride 64 elems, 16B-slot swizzle) ----
template<int ROWS, int NT>
__device__ __forceinline__ void stage_g16(u16* lds, const u16* __restrict__ src,
                                          int ld, int tid) {
  constexpr int UNITS = ROWS * 8;
  constexpr int WV = NT / 64;
  int lane = tid & 63, w = tid >> 6;
  #pragma unroll
  for (int u = 0; u < UNITS / NT; ++u) {
    int base = (u * WV + w) * 64;
    int unit = base + lane;
    int row = unit >> 3, co = unit & 7;
    gload16(src + (long)row * ld + ((co ^ (row & 7)) << 3), lds + base * 8);
  }
}
template<int ROWS, int NT>
__device__ __forceinline__ void stage_f32(u16* lds, const float* __restrict__ src,
                                          int ld, int tid) {
  constexpr int UNITS = ROWS * 8;
  #pragma unroll
  for (int u = 0; u < UNITS / NT; ++u) {
    int unit = tid + u * NT;
    int row = unit >> 3, co = unit & 7;
    const float* g = src + (long)row * ld + (co << 3);
    float4 a = *(const float4*)g;
    float4 b = *(const float4*)(g + 4);
    u32 p[4] = {cvtpk(a.x, a.y), cvtpk(a.z, a.w),
                cvtpk(b.x, b.y), cvtpk(b.z, b.w)};
    *(uint4*)&lds[(row << 6) + ((co ^ (row & 7)) << 3)] = *(const uint4*)p;
  }
}

// ---------------- generic GEMM core: D = A @ B^T (1-phase, small shapes) ------
template<typename AT, typename BT, int BM, int BN, int WM, int WN>
__device__ __forceinline__ void gemm_core(const AT* __restrict__ A, int lda,
                                          const BT* __restrict__ Bt, int ldb, int K,
                                          u16* As, u16* Bs,
                                          f32x4 (&acc)[BM / (WM * 16)][BN / (WN * 16)]) {
  constexpr int NT = WM * WN * 64;
  constexpr int MI = BM / (WM * 16), NJ = BN / (WN * 16);
  int tid = threadIdx.x, lane = tid & 63, wid = tid >> 6;
  int wr = wid % WM, wc = wid / WM;
  int g = lane >> 4, c = lane & 15;
  #pragma unroll
  for (int mi = 0; mi < MI; ++mi)
    #pragma unroll
    for (int nj = 0; nj < NJ; ++nj)
      acc[mi][nj] = f32x4{0.f, 0.f, 0.f, 0.f};
  for (int kb = 0; kb < K; kb += 64) {
    __syncthreads();
    if constexpr (sizeof(AT) == 4) stage_f32<BM, NT>(As, A + kb, lda, tid);
    else                           stage_g16<BM, NT>(As, A + kb, lda, tid);
    if constexpr (sizeof(BT) == 4) stage_f32<BN, NT>(Bs, Bt + kb, ldb, tid);
    else                           stage_g16<BN, NT>(Bs, Bt + kb, ldb, tid);
    __syncthreads();
    #pragma unroll
    for (int kk = 0; kk < 2; ++kk) {
      int sl = ((kk * 4 + g) ^ (c & 7)) << 3;
      short8 af[MI], bfr[NJ];
      #pragma unroll
      for (int mi = 0; mi < MI; ++mi)
        af[mi] = *(const short8*)&As[((wr * (BM / WM) + mi * 16 + c) << 6) + sl];
      #pragma unroll
      for (int nj = 0; nj < NJ; ++nj)
        bfr[nj] = *(const short8*)&Bs[((wc * (BN / WN) + nj * 16 + c) << 6) + sl];
      #pragma unroll
      for (int mi = 0; mi < MI; ++mi)
        #pragma unroll
        for (int nj = 0; nj < NJ; ++nj)
          acc[mi][nj] = mfma16(af[mi], bfr[nj], acc[mi][nj]);
    }
  }
}

// ---------------- fused prep: S cast (768 blocks) + weight transpose ----------
struct TJob { const float* src; u16* dst; int R, C, tile0; };
struct TJobs { TJob j[9]; };

__global__ __launch_bounds__(256) void k_prep(const float* __restrict__ S,
                                              u16* __restrict__ Sb, TJobs jobs) {
  __shared__ float tile[32][33];
  int bid = blockIdx.x;
  if (bid < 768) {  // cast S fp32 -> bf16
    int idx = (bid * 256 + threadIdx.x) * 8;
    float4 a = *(const float4*)(S + idx);
    float4 b = *(const float4*)(S + idx + 4);
    u32 p[4] = {cvtpk(a.x, a.y), cvtpk(a.z, a.w),
                cvtpk(b.x, b.y), cvtpk(b.z, b.w)};
    *(uint4*)(Sb + idx) = *(const uint4*)p;
    return;
  }
  int t = bid - 768;
  int ji = 0;
  #pragma unroll
  for (int k = 1; k < 9; ++k)
    if (t >= jobs.j[k].tile0) ji = k;
  TJob jb = jobs.j[ji];
  int lt = t - jb.tile0;
  int tpr = jb.C >> 5;
  int tr = lt / tpr, tc = lt % tpr;
  int tid = threadIdx.x;
  #pragma unroll
  for (int u = 0; u < 4; ++u) {
    int e = tid + u * 256;
    int r = e >> 5, cc = e & 31;
    tile[r][cc] = jb.src[(long)(tr * 32 + r) * jb.C + tc * 32 + cc];
  }
  __syncthreads();
  #pragma unroll
  for (int u = 0; u < 4; ++u) {
    int e = tid + u * 256;
    int r = e >> 5, cc = e & 31;
    jb.dst[(long)(tc * 32 + r) * jb.R + tr * 32 + cc] = f2bf(tile[cc][r]);
  }
}

// ---------------- G1: unified QKV+iaQ projection (bf16 GEMM, N=2048) ----------
__global__ __launch_bounds__(256) void k_qkv(const u16* __restrict__ Sb,
    const u16* __restrict__ btAll,
    const float* __restrict__ b0, const float* __restrict__ b1,
    const float* __restrict__ b2, const float* __restrict__ b3,
    u16* __restrict__ Qc, u16* __restrict__ Kc, u16* __restrict__ Vt,
    u16* __restrict__ Qi) {
  __shared__ u16 SH[16384];
  int f = blockIdx.x;                       // 384 blocks
  int swz = (f & 7) * 48 + (f >> 3);
  int mb = swz >> 4, nb = swz & 15;
  f32x4 acc[4][4];
  gemm_core<u16, u16, 128, 128, 2, 2>(Sb + (long)mb * 128 * 512, 512,
                                      btAll + (long)nb * 128 * 512, 512, 512,
                                      SH, SH + 8192, acc);
  int z = nb >> 2;
  const float* bias = z == 0 ? b0 : z == 1 ? b1 : z == 2 ? b2 : b3;
  // z==0: Qc scaled by 1/8 * log2(e) so CA softmax can use exp2 directly.
  float scale = z == 0 ? 0.18033688011112042f : (z == 3 ? 0.125f : 1.0f);
  int lane = threadIdx.x & 63, wid = threadIdx.x >> 6;
  int wr = wid & 1, wc = wid >> 1, g = lane >> 4, cl = lane & 15;
  #pragma unroll
  for (int mi = 0; mi < 4; ++mi)
    #pragma unroll
    for (int nj = 0; nj < 4; ++nj)
      #pragma unroll
      for (int r = 0; r < 4; ++r) {
        int row = mb * 128 + wr * 64 + mi * 16 + g * 4 + r;
        int cz = (nb & 3) * 128 + wc * 64 + nj * 16 + cl;
        float v = (acc[mi][nj][r] + bias[cz]) * scale;
        int seq = row / 192, t = row % 192, h = cz >> 6, hd = cz & 63;
        if (z == 0)      Qc[((long)(seq * 8 + h) * 192 + t) * 64 + hd] = f2bf(v);
        else if (z == 1) Kc[((long)(seq * 8 + h) * 192 + t) * 64 + hd] = f2bf(v);
        else if (z == 2) Vt[((long)(seq * 8 + h) * 64 + hd) * 192 + t] = f2bf(v);
        else             Qi[(long)row * 512 + cz] = f2bf(v);
      }
}

// ---------------- G2: CA attention (staged K/V) + uproj tail, one dispatch ----
__global__ __launch_bounds__(256) void k_attn_up(const u16* __restrict__ Qc,
    const u16* __restrict__ Kc, const u16* __restrict__ VtG,
    const int* __restrict__ mask, u16* __restrict__ AC,
    const u16* __restrict__ Qi, const float* __restrict__ wk,
    u16* __restrict__ U, int attnBlocks) {
  __shared__ __align__(16) u16 SH[24960];
  int bid = blockIdx.x;
  int tid = threadIdx.x, lane = tid & 63, w = tid >> 6;
  int g = lane >> 4, c = lane & 15;
  if (bid < attnBlocks) {
    u16* Ks = SH;
    u16* Vs = SH + 12288;
    float* mbf = (float*)(SH + 24576);
    int b = bid >> 3, h = bid & 7;
    int i = b >> 4, j = b & 15;
    int qb = w * 48;

    const u16* Kbase = Kc + (long)(j * 8 + h) * 192 * 64;
    #pragma unroll
    for (int u = 0; u < 6; ++u) {
      int base = (u * 4 + w) * 64;
      int unit = base + lane;
      int row = unit >> 3, co = unit & 7;
      gload16(Kbase + (long)row * 64 + ((co ^ (row & 7)) << 3), Ks + base * 8);
    }
    const u16* Vbase = VtG + (long)(j * 8 + h) * 64 * 192;
    #pragma unroll
    for (int u = 0; u < 6; ++u) {
      int base = (u * 4 + w) * 64;
      int unit = base + lane;
      int row = unit / 24, co = unit - row * 24;
      gload16(Vbase + (long)row * 192 + ((co ^ (row & 7)) << 3), Vs + base * 8);
    }
    short8 bq[3][2];
    const u16* Qbase = Qc + (long)(i * 8 + h) * 192 * 64;
    #pragma unroll
    for (int nj = 0; nj < 3; ++nj)
      #pragma unroll
      for (int ks = 0; ks < 2; ++ks)
        bq[nj][ks] = *(const short8*)(Qbase + (long)(qb + nj * 16 + c) * 64 + ks * 32 + g * 8);
    if (tid < 192) mbf[tid] = mask[(long)b * 192 + tid] ? 0.f : -1e9f;
    __syncthreads();

    f32x4 oa[4][3];
    #pragma unroll
    for (int mi = 0; mi < 4; ++mi)
      #pragma unroll
      for (int nj = 0; nj < 3; ++nj)
        oa[mi][nj] = f32x4{0.f, 0.f, 0.f, 0.f};
    float sm[3] = {0.f, 0.f, 0.f};
    int srcLo = c | ((g & 1) << 5);
    int srcHi = srcLo + 16;
    int hi = g & 2;

    for (int s = 0; s < 6; ++s) {
      short8 ak[2][2];
      #pragma unroll
      for (int kh = 0; kh < 2; ++kh) {
        int row = (2 * s + kh) * 16 + c;
        #pragma unroll
        for (int ks = 0; ks < 2; ++ks)
          ak[kh][ks] = *(const short8*)&Ks[(row << 6) + (((ks * 4 + g) ^ (c & 7)) << 3)];
      }
      f32x4 sa[2][3];
      __builtin_amdgcn_s_setprio(1);
      #pragma unroll
      for (int kh = 0; kh < 2; ++kh)
        #pragma unroll
        for (int nj = 0; nj < 3; ++nj) {
          sa[kh][nj] = mfma16(ak[kh][0], bq[nj][0], f32x4{0.f, 0.f, 0.f, 0.f});
          sa[kh][nj] = mfma16(ak[kh][1], bq[nj][1], sa[kh][nj]);
        }
      __builtin_amdgcn_s_setprio(0);
      u32 pk[2][3][2];
      #pragma unroll
      for (int kh = 0; kh < 2; ++kh) {
        f32x4 m4 = *(const f32x4*)&mbf[(2 * s + kh) * 16 + g * 4];
        #pragma unroll
        for (int nj = 0; nj < 3; ++nj) {
          float p0 = exp2a(sa[kh][nj][0] + m4[0]);
          float p1 = exp2a(sa[kh][nj][1] + m4[1]);
          float p2 = exp2a(sa[kh][nj][2] + m4[2]);
          float p3 = exp2a(sa[kh][nj][3] + m4[3]);
          sm[nj] += (p0 + p1) + (p2 + p3);
          pk[kh][nj][0] = cvtpk(p0, p1);
          pk[kh][nj][1] = cvtpk(p2, p3);
        }
      }
      short8 bfg[3];
      #pragma unroll
      for (int nj = 0; nj < 3; ++nj) {
        u32 w0a = (u32)__shfl((int)pk[0][nj][0], srcLo);
        u32 w0b = (u32)__shfl((int)pk[1][nj][0], srcLo);
        u32 w1a = (u32)__shfl((int)pk[0][nj][1], srcLo);
        u32 w1b = (u32)__shfl((int)pk[1][nj][1], srcLo);
        u32 w2a = (u32)__shfl((int)pk[0][nj][0], srcHi);
        u32 w2b = (u32)__shfl((int)pk[1][nj][0], srcHi);
        u32 w3a = (u32)__shfl((int)pk[0][nj][1], srcHi);
        u32 w3b = (u32)__shfl((int)pk[1][nj][1], srcHi);
        union { u32 u[4]; short8 s8; } bf;
        bf.u[0] = hi ? w0b : w0a;
        bf.u[1] = hi ? w1b : w1a;
        bf.u[2] = hi ? w2b : w2a;
        bf.u[3] = hi ? w3b : w3a;
        bfg[nj] = bf.s8;
      }
      int sl = ((s * 4 + g) ^ (c & 7)) << 3;
      __builtin_amdgcn_s_setprio(1);
      #pragma unroll
      for (int mi = 0; mi < 4; ++mi) {
        short8 av = *(const short8*)&Vs[(mi * 16 + c) * 192 + sl];
        #pragma unroll
        for (int nj = 0; nj < 3; ++nj)
          oa[mi][nj] = mfma16(av, bfg[nj], oa[mi][nj]);
      }
      __builtin_amdgcn_s_setprio(0);
    }
    #pragma unroll
    for (int nj = 0; nj < 3; ++nj) {
      sm[nj] += __shfl_xor(sm[nj], 16);
      sm[nj] += __shfl_xor(sm[nj], 32);
    }
    #pragma unroll
    for (int nj = 0; nj < 3; ++nj) {
      float rs = 1.0f / sm[nj];
      int q = qb + nj * 16 + c;
      u16* dst = AC + ((long)(b * 192 + q)) * 512 + h * 64 + g * 4;
      #pragma unroll
      for (int mi = 0; mi < 4; ++mi) {
        u32 p2[2] = {cvtpk(oa[mi][nj][0] * rs, oa[mi][nj][1] * rs),
                     cvtpk(oa[mi][nj][2] * rs, oa[mi][nj][3] * rs)};
        *(uint2*)(dst + mi * 16) = *(const uint2*)p2;
      }
    }
  } else {
    u16* As = SH;
    u16* Bs = SH + 8192;
    int t = bid - attnBlocks;
    int mb = t % 24, r2 = t / 24;
    int nb = r2 & 3, h = r2 >> 2;
    f32x4 acc[4][4];
    gemm_core<u16, float, 128, 128, 2, 2>(Qi + (long)mb * 128 * 512 + h * 64, 512,
                                          wk + (long)nb * 128 * 512 + h * 64, 512, 64,
                                          As, Bs, acc);
    int wr = w & 1, wc = w >> 1, cl = lane & 15;
    #pragma unroll
    for (int mi = 0; mi < 4; ++mi)
      #pragma unroll
      for (int nj = 0; nj < 4; ++nj)
        #pragma unroll
        for (int r = 0; r < 4; ++r) {
          int row = mb * 128 + wr * 64 + mi * 16 + g * 4 + r;
          int col = nb * 128 + wc * 64 + nj * 16 + cl;
          U[((long)row * 8 + h) * 512 + col] = f2bf(acc[mi][nj][r]);
        }
  }
}

// ---------------- G3: CA out-proj — 256x128 4-phase pipelined GEMM ----------
// 768 blocks (= 3.0 even rounds @1 block/CU), 8 waves (2M x 4N), per-wave
// 128x32 out. LDS 96KB: A dbuf 2x32KB at 0, B dbuf 2x16KB at elem 32768.
// Per K-tile loads in flight: 4 (A) + 2 (B) -> vmcnt(6).
__global__ __launch_bounds__(512, 1) void k_oproj8(const u16* __restrict__ AC,
    const u16* __restrict__ woT, const float* __restrict__ bo,
    u16* __restrict__ S2) {
  extern __shared__ u16 LDS[];
  int f = blockIdx.x;                       // 768 blocks
  int swz = (f & 7) * 96 + (f >> 3);
  int mb = swz >> 2, nb = swz & 3;
  int tid = threadIdx.x, lane = tid & 63, wid = tid >> 6;
  int wr = wid >> 2, wc = wid & 3;
  int g = lane >> 4, c = lane & 15;
  const u16* Abase = AC + (long)mb * 256 * 512;
  const u16* Bbase = woT + (long)nb * 128 * 512;

  auto STAGE_A = [&](int buf, int half, int kt) {
    u16* ldst = LDS + buf * 16384 + half * 8192;
    const u16* gsrc = Abase + (long)half * 128 * 512 + kt * 64;
    #pragma unroll
    for (int u = 0; u < 2; ++u) {
      int unit = tid + u * 512;
      int row = unit >> 3, co = unit & 7;
      gload16(gsrc + (long)row * 512 + ((co ^ (row & 7)) << 3), ldst + unit * 8);
    }
  };
  auto STAGE_B = [&](int buf, int kt) {
    u16* ldst = LDS + 32768 + buf * 8192;
    const u16* gsrc = Bbase + kt * 64;
    #pragma unroll
    for (int u = 0; u < 2; ++u) {
      int unit = tid + u * 512;
      int row = unit >> 3, co = unit & 7;
      gload16(gsrc + (long)row * 512 + ((co ^ (row & 7)) << 3), ldst + unit * 8);
    }
  };

  f32x4 acc[8][2];
  #pragma unroll
  for (int mi = 0; mi < 8; ++mi)
    #pragma unroll
    for (int nj = 0; nj < 2; ++nj)
      acc[mi][nj] = f32x4{0.f, 0.f, 0.f, 0.f};

  // prologue: stage K-tiles 0 and 1 (6 loads each)
  STAGE_A(0, 0, 0); STAGE_A(0, 1, 0); STAGE_B(0, 0);
  STAGE_A(1, 0, 1); STAGE_A(1, 1, 1); STAGE_B(1, 1);
  asm volatile("s_waitcnt vmcnt(6)");
  __builtin_amdgcn_s_barrier();

  short8 aLo[8], aHi[8], b0[2], b1[2];
  for (int t = 0; t < 8; ++t) {
    int buf = t & 1;
    int abase = buf * 16384, bbase = 32768 + buf * 8192;
    // ---- P1: read aLo (m0-3) + b0 (nj0); MFMA acc[m][0] ----
    #pragma unroll
    for (int m = 0; m < 4; ++m)
      #pragma unroll
      for (int kk = 0; kk < 2; ++kk)
        aLo[m * 2 + kk] = *(const short8*)&LDS[abase +
            (wr * 128 + m * 16 + c) * 64 + (((kk * 4 + g) ^ (c & 7)) << 3)];
    #pragma unroll
    for (int kk = 0; kk < 2; ++kk)
      b0[kk] = *(const short8*)&LDS[bbase +
          (wc * 32 + c) * 64 + (((kk * 4 + g) ^ (c & 7)) << 3)];
    __builtin_amdgcn_s_barrier();
    asm volatile("s_waitcnt lgkmcnt(0)");
    __builtin_amdgcn_sched_barrier(0);
    __builtin_amdgcn_s_setprio(1);
    #pragma unroll
    for (int m = 0; m < 4; ++m)
      #pragma unroll
      for (int kk = 0; kk < 2; ++kk)
        acc[m][0] = mfma16(aLo[m * 2 + kk], b0[kk], acc[m][0]);
    __builtin_amdgcn_s_setprio(0);
    __builtin_amdgcn_s_barrier();
    // ---- P2: read aHi (m4-7); MFMA acc[4+m][0] ----
    #pragma unroll
    for (int m = 0; m < 4; ++m)
      #pragma unroll
      for (int kk = 0; kk < 2; ++kk)
        aHi[m * 2 + kk] = *(const short8*)&LDS[abase +
            (wr * 128 + (4 + m) * 16 + c) * 64 + (((kk * 4 + g) ^ (c & 7)) << 3)];
    __builtin_amdgcn_s_barrier();
    asm volatile("s_waitcnt lgkmcnt(0)");
    __builtin_amdgcn_sched_barrier(0);
    __builtin_amdgcn_s_setprio(1);
    #pragma unroll
    for (int m = 0; m < 4; ++m)
      #pragma unroll
      for (int kk = 0; kk < 2; ++kk)
        acc[4 + m][0] = mfma16(aHi[m * 2 + kk], b0[kk], acc[4 + m][0]);
    __builtin_amdgcn_s_setprio(0);
    __builtin_amdgcn_s_barrier();
    // ---- P3: read b1 (nj1); stage A(t+2); MFMA acc[m][1] ----
    #pragma unroll
    for (int kk = 0; kk < 2; ++kk)
      b1[kk] = *(const short8*)&LDS[bbase +
          (wc * 32 + 16 + c) * 64 + (((kk * 4 + g) ^ (c & 7)) << 3)];
    if (t < 6) {
      STAGE_A(buf, 0, t + 2);
      STAGE_A(buf, 1, t + 2);
    }
    __builtin_amdgcn_s_barrier();
    asm volatile("s_waitcnt lgkmcnt(0)");
    __builtin_amdgcn_sched_barrier(0);
    __builtin_amdgcn_s_setprio(1);
    #pragma unroll
    for (int m = 0; m < 4; ++m)
      #pragma unroll
      for (int kk = 0; kk < 2; ++kk)
        acc[m][1] = mfma16(aLo[m * 2 + kk], b1[kk], acc[m][1]);
    __builtin_amdgcn_s_setprio(0);
    __builtin_amdgcn_s_barrier();
    // ---- P4: stage B(t+2); MFMA acc[4+m][1]; end-of-tile wait ----
    if (t < 6) STAGE_B(buf, t + 2);
    __builtin_amdgcn_s_setprio(1);
    #pragma unroll
    for (int m = 0; m < 4; ++m)
      #pragma unroll
      for (int kk = 0; kk < 2; ++kk)
        acc[4 + m][1] = mfma16(aHi[m * 2 + kk], b1[kk], acc[4 + m][1]);
    __builtin_amdgcn_s_setprio(0);
    if (t < 6)      asm volatile("s_waitcnt vmcnt(6)");
    else if (t == 6) asm volatile("s_waitcnt vmcnt(0)");
    if (t < 7) __builtin_amdgcn_s_barrier();
  }
  // epilogue
  #pragma unroll
  for (int nj = 0; nj < 2; ++nj) {
    int col = nb * 128 + wc * 32 + nj * 16 + c;
    float bv = bo[col];
    #pragma unroll
    for (int mi = 0; mi < 8; ++mi)
      #pragma unroll
      for (int r = 0; r < 4; ++r) {
        int row = mb * 256 + wr * 128 + mi * 16 + g * 4 + r;
        S2[(long)row * 512 + col] = f2bf(acc[mi][nj][r] + bv);
      }
  }
}

// ---------------- G5: IA attention (MFMA logits + softmax + weighted-sum) -----
__global__ __launch_bounds__(256) void k_ia_attn(const u16* __restrict__ S2,
    const u16* __restrict__ U, const u16* __restrict__ Qi,
    const float* __restrict__ bk, u16* __restrict__ Y) {
  __shared__ u16 s2[16 * 520];
  __shared__ float Lp[4][16][17];
  __shared__ float aL[8][16];
  __shared__ float cL[8];
  int tok = blockIdx.x;
  int tid = threadIdx.x, lane = tid & 63, w = tid >> 6;
  {
    const u16* src = S2 + (long)tok * 512;
    #pragma unroll
    for (int u = 0; u < 4; ++u) {
      int e = tid + u * 256;
      int r = e >> 6, cc = (e & 63) << 3;
      *(uint4*)&s2[r * 520 + cc] = *(const uint4*)(src + (long)r * 3072 * 512 + cc);
    }
  }
  if (w == 0) {
    int h = lane >> 3, p = lane & 7;
    short8 qv = *(const short8*)(Qi + (long)tok * 512 + h * 64 + p * 8);
    const float* bkp = bk + h * 64 + p * 8;
    float s = 0.f;
    #pragma unroll
    for (int v = 0; v < 8; ++v) s += bf2f((u16)qv[v]) * bkp[v];
    s += __shfl_xor(s, 1); s += __shfl_xor(s, 2); s += __shfl_xor(s, 4);
    if (p == 0) cL[h] = s;
  }
  __syncthreads();
  {
    int g = lane >> 4, c = lane & 15;
    const u16* Ub = U + (long)tok * 4096 + (long)(c & 7) * 512;
    f32x4 accL = {0.f, 0.f, 0.f, 0.f};
    #pragma unroll
    for (int kk = 0; kk < 4; ++kk) {
      int d = w * 128 + kk * 32 + g * 8;
      short8 aS = *(const short8*)&s2[c * 520 + d];
      short8 bU = *(const short8*)(Ub + d);
      accL = mfma16(aS, bU, accL);
    }
    #pragma unroll
    for (int r = 0; r < 4; ++r) Lp[w][g * 4 + r][c] = accL[r];
  }
  __syncthreads();
  if (w == 0) {
    int h = lane & 7, i0 = lane >> 3;
    float L0 = Lp[0][i0][h] + Lp[1][i0][h] + Lp[2][i0][h] + Lp[3][i0][h] + cL[h];
    float L1 = Lp[0][i0 + 8][h] + Lp[1][i0 + 8][h] + Lp[2][i0 + 8][h] +
               Lp[3][i0 + 8][h] + cL[h];
    float e0 = __expf(L0), e1 = __expf(L1);
    float s = e0 + e1;
    s += __shfl_xor(s, 8); s += __shfl_xor(s, 16); s += __shfl_xor(s, 32);
    float rs = 1.0f / s;
    aL[h][i0] = e0 * rs;
    aL[h][i0 + 8] = e1 * rs;
  }
  __syncthreads();
  {
    int h = tid & 7, d0 = (tid >> 3) << 4;
    float y[16];
    #pragma unroll
    for (int v = 0; v < 16; ++v) y[v] = 0.f;
    #pragma unroll
    for (int i = 0; i < 16; ++i) {
      float a = aL[h][i];
      short8 v0 = *(const short8*)&s2[i * 520 + d0];
      short8 v1 = *(const short8*)&s2[i * 520 + d0 + 8];
      #pragma unroll
      for (int v = 0; v < 8; ++v) {
        y[v]     += a * bf2f((u16)v0[v]);
        y[8 + v] += a * bf2f((u16)v1[v]);
      }
    }
    u32 o[8];
    #pragma unroll
    for (int v = 0; v < 8; ++v) o[v] = cvtpk(y[2 * v], y[2 * v + 1]);
    u16* dst = Y + ((long)tok * 8 + h) * 512 + d0;
    *(uint4*)dst = *(const uint4*)&o[0];
    *(uint4*)(dst + 8) = *(const uint4*)&o[4];
  }
}

// ---------------- G6: attn_h = y_h @ Wv_h + bv ----------------
__global__ __launch_bounds__(256) void k_vapply(const u16* __restrict__ Y,
    const u16* __restrict__ wvT, const float* __restrict__ bv,
    u16* __restrict__ AO) {
  __shared__ u16 As[128 * 64];
  __shared__ u16 Bs[64 * 64];
  int mb = blockIdx.x, h = blockIdx.z;
  f32x4 acc[2][4];
  gemm_core<u16, u16, 128, 64, 4, 1>(Y + (long)mb * 128 * 4096 + h * 512, 4096,
                                     wvT + (long)h * 64 * 512, 512, 512,
                                     As, Bs, acc);
  int lane = threadIdx.x & 63, wid = threadIdx.x >> 6;
  int g = lane >> 4, cl = lane & 15;
  #pragma unroll
  for (int mi = 0; mi < 2; ++mi)
    #pragma unroll
    for (int nj = 0; nj < 4; ++nj)
      #pragma unroll
      for (int r = 0; r < 4; ++r) {
        int row = mb * 128 + wid * 32 + mi * 16 + g * 4 + r;
        int col = h * 64 + nj * 16 + cl;
        AO[(long)row * 512 + col] = f2bf(acc[mi][nj][r] + bv[col]);
      }
}

// ---------------- generic [3072,K]@[K,512] -> fp32, split-K=2 over grid.y -----
__global__ __launch_bounds__(256) void k_gemm_f32out(const u16* __restrict__ A, int K,
    const u16* __restrict__ BT, const float* __restrict__ bias,
    float* __restrict__ out) {
  __shared__ u16 As[128 * 64];
  __shared__ u16 Bs[64 * 64];
  int f = blockIdx.x;                       // 192 blocks per part
  int ks = blockIdx.y;
  int swz = (f & 7) * 24 + (f >> 3);
  int mb = swz >> 3, nb = swz & 7;
  int Kh = K >> 1;
  f32x4 acc[4][2];
  gemm_core<u16, u16, 128, 64, 2, 2>(A + (long)mb * 128 * K + (long)ks * Kh, K,
                                     BT + (long)nb * 64 * K + (long)ks * Kh, K,
                                     Kh, As, Bs, acc);
  out += (long)ks * 3072 * 512;
  int lane = threadIdx.x & 63, wid = threadIdx.x >> 6;
  int wr = wid & 1, wc = wid >> 1, g = lane >> 4, cl = lane & 15;
  #pragma unroll
  for (int mi = 0; mi < 4; ++mi)
    #pragma unroll
    for (int nj = 0; nj < 2; ++nj)
      #pragma unroll
      for (int r = 0; r < 4; ++r) {
        int row = mb * 128 + wr * 64 + mi * 16 + g * 4 + r;
        int col = nb * 64 + wc * 32 + nj * 16 + cl;
        float bv = ks == 0 ? bias[col] : 0.f;
        out[(long)row * 512 + col] = acc[mi][nj][r] + bv;
      }
}

// ---------------- G9: FFN1 with ReLU -> bf16 (XCD swizzle) ----------------
__global__ __launch_bounds__(256) void k_ffn1(const u16* __restrict__ A,
    const u16* __restrict__ BT, const float* __restrict__ bias,
    u16* __restrict__ out) {
  __shared__ u16 As[128 * 64];
  __shared__ u16 Bs[128 * 64];
  int f = blockIdx.x;                       // 384 blocks
  int swz = (f & 7) * 48 + (f >> 3);
  int mb = swz >> 4, nb = swz & 15;
  f32x4 acc[4][4];
  gemm_core<u16, u16, 128, 128, 2, 2>(A + (long)mb * 128 * 512, 512,
                                      BT + (long)nb * 128 * 512, 512, 512,
                                      As, Bs, acc);
  int lane = threadIdx.x & 63, wid = threadIdx.x >> 6;
  int wr = wid & 1, wc = wid >> 1, g = lane >> 4, cl = lane & 15;
  #pragma unroll
  for (int mi = 0; mi < 4; ++mi)
    #pragma unroll
    for (int nj = 0; nj < 4; ++nj)
      #pragma unroll
      for (int r = 0; r < 4; ++r) {
        int row = mb * 128 + wr * 64 + mi * 16 + g * 4 + r;
        int col = nb * 128 + wc * 64 + nj * 16 + cl;
        out[(long)row * 2048 + col] = f2bf(fmaxf(acc[mi][nj][r] + bias[col], 0.f));
      }
}

// ---------------- LayerNorm over D=512 of (X1+X2[+X3]) ----------------
__global__ __launch_bounds__(256) void k_ln(const float* __restrict__ X1,
    const float* __restrict__ X2, const float* __restrict__ X3,
    const float* __restrict__ gg, const float* __restrict__ bb,
    float* __restrict__ outF, u16* __restrict__ outB) {
  __shared__ float red[8];
  int row = blockIdx.x, tid = threadIdx.x;
  long base = (long)row * 512;
  float x0 = X1[base + tid] + X2[base + tid];
  float x1 = X1[base + tid + 256] + X2[base + tid + 256];
  if (X3) {
    x0 += X3[base + tid];
    x1 += X3[base + tid + 256];
  }
  float s = x0 + x1, ss = x0 * x0 + x1 * x1;
  #pragma unroll
  for (int m = 1; m <= 32; m <<= 1) {
    s += __shfl_xor(s, m);
    ss += __shfl_xor(ss, m);
  }
  int w = tid >> 6;
  if ((tid & 63) == 0) { red[w] = s; red[4 + w] = ss; }
  __syncthreads();
  s = red[0] + red[1] + red[2] + red[3];
  ss = red[4] + red[5] + red[6] + red[7];
  float mu = s * (1.0f / 512.0f);
  float var = ss * (1.0f / 512.0f) - mu * mu;
  float rstd = 1.0f / sqrtf(var + 1e-6f);
  float y0 = (x0 - mu) * rstd * gg[tid] + bb[tid];
  float y1 = (x1 - mu) * rstd * gg[tid + 256] + bb[tid + 256];
  if (outF) { outF[base + tid] = y0; outF[base + tid + 256] = y1; }
  if (outB) { outB[base + tid] = f2bf(y0); outB[base + tid + 256] = f2bf(y1); }
}

// ---------------- host orchestration ----------------
extern "C" void kernel_launch(void* const* d_in, const int* in_sizes, int n_in,
                              void* d_out, int out_size, void* d_ws, size_t ws_size,
                              hipStream_t stream) {
  const float* S      = (const float*)d_in[0];
  const int*   maskp  = (const int*)d_in[1];
  const float* ca_wq  = (const float*)d_in[3];
  const float* ca_bq  = (const float*)d_in[4];
  const float* ca_wk  = (const float*)d_in[5];
  const float* ca_bk  = (const float*)d_in[6];
  const float* ca_wv  = (const float*)d_in[7];
  const float* ca_bv  = (const float*)d_in[8];
  const float* ca_wo  = (const float*)d_in[9];
  const float* ca_bo  = (const float*)d_in[10];
  const float* ia_wq  = (const float*)d_in[11];
  const float* ia_bq  = (const float*)d_in[12];
  const float* ia_wk  = (const float*)d_in[13];
  const float* ia_bk  = (const float*)d_in[14];
  const float* ia_wv  = (const float*)d_in[15];
  const float* ia_bv  = (const float*)d_in[16];
  const float* ia_wo  = (const float*)d_in[17];
  const float* ia_bo  = (const float*)d_in[18];
  const float* ffn_w1 = (const float*)d_in[19];
  const float* ffn_b1 = (const float*)d_in[20];
  const float* ffn_w2 = (const float*)d_in[21];
  const float* ffn_b2 = (const float*)d_in[22];
  const float* ln1_g  = (const float*)d_in[23];
  const float* ln1_b  = (const float*)d_in[24];
  const float* ln2_g  = (const float*)d_in[25];
  const float* ln2_b  = (const float*)d_in[26];

  char* ws = (char*)d_ws;
  constexpr size_t OFF_WQT  = 0;
  constexpr size_t OFF_WOTC = 2097152;
  constexpr size_t OFF_WVTI = 2621440;
  constexpr size_t OFF_WOTI = 3145728;
  constexpr size_t OFF_W1T  = 3670016;
  constexpr size_t OFF_W2T  = 5767168;
  constexpr size_t OFF_QC   = 7864320;
  constexpr size_t OFF_KC   = 11010048;
  constexpr size_t OFF_VT   = 14155776;
  constexpr size_t OFF_QI   = 17301504;
  constexpr size_t OFF_AC   = 20447232;
  constexpr size_t OFF_S2   = 70778880;
  constexpr size_t OFF_UBIG = 121110528;
  constexpr size_t NEED_BIG = OFF_UBIG + 25165824;
  constexpr size_t OFF_SB   = OFF_AC;
  constexpr size_t OFF_Y    = OFF_AC + 25165824;
  constexpr size_t OFF_AO   = OFF_QI;
  constexpr size_t OFF_IAO  = OFF_QC;           // 2 parts x 6291456 B
  constexpr size_t OFF_SNF  = OFF_S2;
  constexpr size_t OFF_SNB  = OFF_VT + 6291456;
  constexpr size_t OFF_HFF  = OFF_S2 + 6291456;
  constexpr size_t OFF_FFO  = OFF_HFF + 12582912; // 2 parts x 6291456 B

  u16* wqT  = (u16*)(ws + OFF_WQT);
  u16* woTc = (u16*)(ws + OFF_WOTC);
  u16* wvTi = (u16*)(ws + OFF_WVTI);
  u16* woTi = (u16*)(ws + OFF_WOTI);
  u16* w1T  = (u16*)(ws + OFF_W1T);
  u16* w2T  = (u16*)(ws + OFF_W2T);
  u16* Qc   = (u16*)(ws + OFF_QC);
  u16* Kc   = (u16*)(ws + OFF_KC);
  u16* Vt   = (u16*)(ws + OFF_VT);
  u16* Qi   = (u16*)(ws + OFF_QI);
  u16* AC   = (u16*)(ws + OFF_AC);
  u16* Sb   = (u16*)(ws + OFF_SB);
  u16* S2   = (u16*)(ws + OFF_S2);
  u16* Y    = (u16*)(ws + OFF_Y);
  u16* AO   = (u16*)(ws + OFF_AO);
  float* IAO = (float*)(ws + OFF_IAO);
  float* SNF = (float*)(ws + OFF_SNF);
  u16* SNB  = (u16*)(ws + OFF_SNB);
  u16* HFF  = (u16*)(ws + OFF_HFF);
  float* FFO = (float*)(ws + OFF_FFO);

  bool bigws = ws_size >= NEED_BIG;
  u16* U = bigws ? (u16*)(ws + OFF_UBIG) : (u16*)(ws + OFF_AC);

  static bool attrDone = false;
  if (!attrDone) {
    (void)hipFuncSetAttribute(reinterpret_cast<const void*>(&k_oproj8),
                              hipFuncAttributeMaxDynamicSharedMemorySize, 98304);
    attrDone = true;
  }

  TJobs tj;
  int t0 = 0;
  auto SET = [&](int k, const float* s, u16* d, int R, int C) {
    tj.j[k].src = s; tj.j[k].dst = d; tj.j[k].R = R; tj.j[k].C = C; tj.j[k].tile0 = t0;
    t0 += (R / 32) * (C / 32);
  };
  SET(0, ca_wq, wqT, 512, 512);
  SET(1, ca_wk, wqT + 262144, 512, 512);
  SET(2, ca_wv, wqT + 524288, 512, 512);
  SET(3, ia_wq, wqT + 786432, 512, 512);
  SET(4, ca_wo, woTc, 512, 512);
  SET(5, ia_wv, wvTi, 512, 512);
  SET(6, ia_wo, woTi, 512, 512);
  SET(7, ffn_w1, w1T, 512, 2048);
  SET(8, ffn_w2, w2T, 2048, 512);

  k_prep<<<dim3(768 + t0), 256, 0, stream>>>(S, Sb, tj);
  k_qkv<<<dim3(384), 256, 0, stream>>>(Sb, wqT, ca_bq, ca_bk, ca_bv, ia_bq,
                                       Qc, Kc, Vt, Qi);
  if (bigws) {
    k_attn_up<<<dim3(2816), 256, 0, stream>>>(Qc, Kc, Vt, maskp, AC, Qi, ia_wk,
                                              U, 2048);
    k_oproj8<<<dim3(768), 512, 98304, stream>>>(AC, woTc, ca_bo, S2);
  } else {
    k_attn_up<<<dim3(2048), 256, 0, stream>>>(Qc, Kc, Vt, maskp, AC, Qi, ia_wk,
                                              U, 2048);
    k_oproj8<<<dim3(768), 512, 98304, stream>>>(AC, woTc, ca_bo, S2);
    k_attn_up<<<dim3(768), 256, 0, stream>>>(Qc, Kc, Vt, maskp, AC, Qi, ia_wk,
                                             U, 0);
  }
  k_ia_attn<<<dim3(3072), 256, 0, stream>>>(S2, U, Qi, ia_bk, Y);
  k_vapply<<<dim3(24, 1, 8), 256, 0, stream>>>(Y, wvTi, ia_bv, AO);
  k_gemm_f32out<<<dim3(192, 2), 256, 0, stream>>>(AO, 512, woTi, ia_bo, IAO);
  k_ln<<<dim3(3072), 256, 0, stream>>>(S, IAO, IAO + 3072 * 512, ln1_g, ln1_b,
                                       SNF, SNB);
  k_ffn1<<<dim3(384), 256, 0, stream>>>(SNB, w1T, ffn_b1, HFF);
  k_gemm_f32out<<<dim3(192, 2), 256, 0, stream>>>(HFF, 2048, w2T, ffn_b2, FFO);
  k_ln<<<dim3(3072), 256, 0, stream>>>(SNF, FFO, FFO + 3072 * 512, ln2_g, ln2_b,
                                       (float*)d_out, nullptr);
}